// Round 2
// baseline (1123.200 us; speedup 1.0000x reference)
//
#include <hip/hip_runtime.h>
#include <hip/hip_bf16.h>
#include <stdint.h>

#define N_CLAIM    100000
#define N_ENTITY   200000
#define N_EVIDENCE 150000
#define NEDGE      2000000
#define F          64
#define NT         550000      // concat dst: t0 claim [0,100K) t1 claim [100K,200K) t2 ent [200K,400K) t3 evid [400K,550K)
#define BATCH      50000

#define EQ4    (NEDGE / 4)     // 500000 int4 groups per edge type
#define NSCAN  538             // ceil(550000/1024)
#define NBITS_W 3136           // ceil(100000/32) words for claim bitmask

static __device__ __forceinline__ float b2f(unsigned short u){
  return __uint_as_float(((unsigned int)u) << 16);
}
static __device__ __forceinline__ unsigned short f2b(float f){
  unsigned int x = __float_as_uint(f);
  x += 0x7fffu + ((x >> 16) & 1u);   // RNE
  return (unsigned short)(x >> 16);
}

// ---------------- fp32 -> bf16 cast ----------------
__global__ void k_cast(const float* __restrict__ in, unsigned short* __restrict__ out, int n4){
  int i = blockIdx.x * blockDim.x + threadIdx.x;
  if (i >= n4) return;
  float4 v = ((const float4*)in)[i];
  ushort4 o;
  o.x = f2b(v.x); o.y = f2b(v.y); o.z = f2b(v.z); o.w = f2b(v.w);
  ((ushort4*)out)[i] = o;
}

// ---------------- used-claim bitmask + compaction ----------------
__global__ void k_mark(const int* __restrict__ cbi, unsigned int* __restrict__ bits){
  int i = blockIdx.x * blockDim.x + threadIdx.x;
  if (i < BATCH){
    int c = cbi[i];
    atomicOr(&bits[c >> 5], 1u << (c & 31));
  }
}
__global__ void k_rank(const unsigned int* __restrict__ bits, int* __restrict__ rank,
                       int* __restrict__ list, int* __restrict__ nu){
  int i = blockIdx.x * blockDim.x + threadIdx.x;
  if (i < N_CLAIM && ((bits[i >> 5] >> (i & 31)) & 1u)){
    int r = atomicAdd(nu, 1);
    rank[i] = r;
    list[r] = i;
  }
}

// ---------------- CSR build: direct global-atomic two-pass ----------------
// pass 1: degree count. Fire-and-forget atomics (no return value -> no waits),
// int4-vectorized dst loads, filter dead claim-dst edges via L1-resident bitmask.
__global__ __launch_bounds__(256) void k_deg(const int* __restrict__ ei,
                                             const unsigned int* __restrict__ bits,
                                             int* __restrict__ deg){
  int tid = blockIdx.x * 256 + threadIdx.x;
  if (tid >= 4 * EQ4) return;
  int t  = tid / EQ4;
  int e4 = (tid - t * EQ4) * 4;
  const int toff[4] = {0, N_CLAIM, 2*N_CLAIM, 2*N_CLAIM + N_ENTITY};
  int4 d = *(const int4*)(ei + (size_t)t * 2 * NEDGE + NEDGE + e4);
  int off = toff[t];
  bool isclaim = (t < 2);
  #pragma unroll
  for (int k = 0; k < 4; ++k){
    int dst = (&d.x)[k];
    if (!isclaim || ((bits[dst >> 5] >> (dst & 31)) & 1u))
      atomicAdd(&deg[dst + off], 1);
  }
}

// hierarchical exclusive scan of deg[NT] -> R (row ptr) and cur (fill cursors)
__global__ __launch_bounds__(1024) void k_s1(const int* __restrict__ deg, int* __restrict__ bsum){
  __shared__ int s[1024];
  int b = blockIdx.x, tid = threadIdx.x;
  int i = b * 1024 + tid;
  s[tid] = (i < NT) ? deg[i] : 0;
  __syncthreads();
  for (int off = 512; off; off >>= 1){
    if (tid < off) s[tid] += s[tid + off];
    __syncthreads();
  }
  if (tid == 0) bsum[b] = s[0];
}

__global__ __launch_bounds__(1024) void k_s2(const int* __restrict__ bsum,
                                             int* __restrict__ bbase, int* __restrict__ R){
  __shared__ int s[1024];
  int tid = threadIdx.x;
  int c = (tid < NSCAN) ? bsum[tid] : 0;
  s[tid] = c;
  __syncthreads();
  for (int off = 1; off < 1024; off <<= 1){
    int t = (tid >= off) ? s[tid - off] : 0;
    __syncthreads();
    s[tid] += t;
    __syncthreads();
  }
  if (tid < NSCAN) bbase[tid] = s[tid] - c;
  if (tid == 1023) R[NT] = s[1023];
}

__global__ __launch_bounds__(1024) void k_s3(const int* __restrict__ deg,
                                             const int* __restrict__ bbase,
                                             int* __restrict__ R, int* __restrict__ cur){
  __shared__ int s[1024];
  int b = blockIdx.x, tid = threadIdx.x;
  int i = b * 1024 + tid;
  int v = (i < NT) ? deg[i] : 0;
  s[tid] = v;
  __syncthreads();
  for (int off = 1; off < 1024; off <<= 1){
    int t = (tid >= off) ? s[tid - off] : 0;
    __syncthreads();
    s[tid] += t;
    __syncthreads();
  }
  if (i < NT){
    int r = bbase[b] + s[tid] - v;
    R[i] = r;
    cur[i] = r;
  }
}

// pass 2: scatter src into col via cursor atomics.
__global__ __launch_bounds__(256) void k_fill(const int* __restrict__ ei,
                                              const unsigned int* __restrict__ bits,
                                              int* __restrict__ cur,
                                              int* __restrict__ col){
  int tid = blockIdx.x * 256 + threadIdx.x;
  if (tid >= 4 * EQ4) return;
  int t  = tid / EQ4;
  int e4 = (tid - t * EQ4) * 4;
  const int toff[4] = {0, N_CLAIM, 2*N_CLAIM, 2*N_CLAIM + N_ENTITY};
  int4 d = *(const int4*)(ei + (size_t)t * 2 * NEDGE + NEDGE + e4);
  int4 sr = *(const int4*)(ei + (size_t)t * 2 * NEDGE + e4);
  int off = toff[t];
  bool isclaim = (t < 2);
  #pragma unroll
  for (int k = 0; k < 4; ++k){
    int dst = (&d.x)[k];
    if (!isclaim || ((bits[dst >> 5] >> (dst & 31)) & 1u)){
      int o = atomicAdd(&cur[dst + off], 1);
      col[o] = (&sr.x)[k];
    }
  }
}

// ---- mean aggregation: 4 dst rows per wave, 16 lanes x 8B per row, no cross-row reduce ----
__global__ __launch_bounds__(256) void k_agg(const unsigned short* __restrict__ X0,
                                             const unsigned short* __restrict__ X1,
                                             const int* __restrict__ R,
                                             const int* __restrict__ col,
                                             unsigned short* __restrict__ M0,
                                             unsigned short* __restrict__ M1,
                                             const int* __restrict__ list,
                                             const int* __restrict__ nu_ptr,
                                             int RbA, int RbB, int nd0_param, int njobs_param){
  int tid  = threadIdx.x;
  int lane = tid & 63;
  int g    = lane >> 4;          // row group 0..3
  int fl   = lane & 15;          // feature slot: features [4fl, 4fl+4)
  int wv   = (int)blockIdx.x * 4 + (tid >> 6);
  int nu     = list ? *nu_ptr : 0;
  int njobs  = list ? 2 * nu : njobs_param;
  int nd0    = list ? nu : nd0_param;
  int j = wv * 4 + g;
  bool active = j < njobs;
  int sub_t = 0, idx = 0, row = 0, node = 0;
  if (active){
    sub_t = (j >= nd0) ? 1 : 0;
    idx = j - (sub_t ? nd0 : 0);
    row = list ? list[idx] : idx;
    node = (sub_t ? RbB : RbA) + row;
  }
  const unsigned short* X = sub_t ? X1 : X0;
  unsigned short* Mo = sub_t ? M1 : M0;
  int rbeg = 0, rend = 0;
  if (active){ rbeg = R[node]; rend = R[node + 1]; }
  int deg = rend - rbeg;
  float4 acc = {0.f, 0.f, 0.f, 0.f};
  for (int p = rbeg; p < rend; p += 8){
    int nb = rend - p; if (nb > 8) nb = 8;
    int cid = 0;
    if (fl < nb) cid = col[p + fl];      // 1 coalesced id prefetch per 8 edges
    #pragma unroll
    for (int k = 0; k < 8; ++k){
      int c = __shfl(cid, (g << 4) + k, 64);
      if (k < nb){
        uint2 d = *(const uint2*)(X + c * F + fl * 4);
        acc.x += __uint_as_float(d.x << 16);
        acc.y += __uint_as_float(d.x & 0xffff0000u);
        acc.z += __uint_as_float(d.y << 16);
        acc.w += __uint_as_float(d.y & 0xffff0000u);
      }
    }
  }
  if (active){
    float r = deg ? (1.0f / (float)deg) : 0.f;
    ushort4 o;
    o.x = f2b(acc.x * r); o.y = f2b(acc.y * r);
    o.z = f2b(acc.z * r); o.w = f2b(acc.w * r);
    *(ushort4*)(Mo + (long long)idx * F + fl * 4) = o;
  }
}

// ---- fused multi-source GEMM: H = act(sum_j Aj@Wj + bias) ----
typedef __bf16 bf16x8 __attribute__((ext_vector_type(8)));
typedef float  f32x4  __attribute__((ext_vector_type(4)));
#define WT_STRIDE 72

__global__ __launch_bounds__(256) void k_gemm(
    const unsigned short* __restrict__ A0, const unsigned short* __restrict__ A1,
    const unsigned short* __restrict__ A2, const unsigned short* __restrict__ A3,
    const float* __restrict__ W0, const float* __restrict__ W1,
    const float* __restrict__ W2, const float* __restrict__ W3,
    const float* __restrict__ b0, const float* __restrict__ b1,
    unsigned short* __restrict__ Hout,
    const int* __restrict__ Alist, int amask,
    const int* __restrict__ Mptr, int Mparam, int ns, int relu)
{
  int M = Mptr ? *Mptr : Mparam;
  if ((int)blockIdx.x * 64 >= M) return;     // block-uniform early exit
  __shared__ __align__(16) unsigned short WT[4 * 64 * WT_STRIDE];
  const float* Ws[4] = {W0, W1, W2, W3};
  const unsigned short* As[4] = {A0, A1, A2, A3};
  int tid = threadIdx.x;
  for (int j = 0; j < ns; j++){
    const float* Wj = Ws[j];
    #pragma unroll
    for (int q = 0; q < 16; q++){
      int idx = q * 256 + tid;
      int k = idx >> 6, n = idx & 63;
      WT[j * 64 * WT_STRIDE + n * WT_STRIDE + k] = f2b(Wj[idx]);
    }
  }
  __syncthreads();
  int wave = tid >> 6, lane = tid & 63;
  int quad = lane >> 4, l16 = lane & 15;
  int m0 = blockIdx.x * 64 + wave * 16;
  int arow = m0 + l16; if (arow >= M) arow = M - 1;
  int arows[4];
  #pragma unroll
  for (int j = 0; j < 4; j++)
    arows[j] = ((amask >> j) & 1) ? Alist[arow] : arow;
  f32x4 z = {0.f, 0.f, 0.f, 0.f};
  f32x4 acc[4] = {z, z, z, z};
  for (int j = 0; j < ns; j++){
    const unsigned short* Aj = As[j];
    #pragma unroll
    for (int kk = 0; kk < 64; kk += 32){
      bf16x8 af = *(const bf16x8*)(Aj + (long long)arows[j] * F + kk + quad * 8);
      #pragma unroll
      for (int c = 0; c < 4; c++){
        const unsigned short* bp = &WT[j * 64 * WT_STRIDE + (c * 16 + l16) * WT_STRIDE + kk + quad * 8];
        bf16x8 bfr = *(const bf16x8*)bp;
        acc[c] = __builtin_amdgcn_mfma_f32_16x16x32_bf16(af, bfr, acc[c], 0, 0, 0);
      }
    }
  }
  #pragma unroll
  for (int c = 0; c < 4; c++){
    int n = c * 16 + l16;
    float bv = b0[n] + (b1 ? b1[n] : 0.f);
    #pragma unroll
    for (int r = 0; r < 4; r++){
      int row = m0 + quad * 4 + r;
      if (row < M){
        float v = acc[c][r] + bv;
        if (relu) v = fmaxf(v, 0.f);
        Hout[(long long)row * F + n] = f2b(v);
      }
    }
  }
}

// ---------------- final classifier: wave per batch row; fp32 out ----------------
__global__ void k_out(const unsigned short* __restrict__ h2,
                      const int* __restrict__ cbi,
                      const int* __restrict__ rank,
                      const float* __restrict__ Wc,
                      const float* __restrict__ bcp,
                      float* __restrict__ out){
  int w = (int)(((unsigned)blockIdx.x * blockDim.x + threadIdx.x) >> 6);
  int lane = threadIdx.x & 63;
  if (w >= BATCH) return;
  int rk = rank[cbi[w]];
  float v = b2f(h2[(long long)rk * F + lane]);
  float p0 = v * Wc[lane * 2];
  float p1 = v * Wc[lane * 2 + 1];
  for (int off = 32; off; off >>= 1){
    p0 += __shfl_xor(p0, off, 64);
    p1 += __shfl_xor(p1, off, 64);
  }
  if (lane == 0){
    out[2 * w]     = p0 + bcp[0];
    out[2 * w + 1] = p1 + bcp[1];
  }
}

extern "C" void kernel_launch(void* const* d_in, const int* in_sizes, int n_in,
                              void* d_out, int out_size, void* d_ws, size_t ws_size,
                              hipStream_t stream)
{
  const float* x_c = (const float*)d_in[0];
  const float* x_e = (const float*)d_in[1];
  const float* x_v = (const float*)d_in[2];
  const int*   ei  = (const int*)d_in[3];
  const int*   cbi = (const int*)d_in[4];
  const float* Wl1 = (const float*)d_in[5];
  const float* bl1 = (const float*)d_in[6];
  const float* Wr1 = (const float*)d_in[7];
  const float* Wl2 = (const float*)d_in[8];
  const float* bl2 = (const float*)d_in[9];
  const float* Wr2 = (const float*)d_in[10];
  const float* Wc  = (const float*)d_in[11];
  const float* bc  = (const float*)d_in[12];
  float* out = (float*)d_out;

  char* ws = (char*)d_ws;
  size_t off = 0;
  auto alloc = [&](size_t bytes) -> char* {
    char* p = ws + off;
    off += (bytes + 255) & ~(size_t)255;
    return p;
  };
  int* R       = (int*)alloc((size_t)(NT + 1) * 4);
  int* deg     = (int*)alloc((size_t)NT * 4);
  int* cur     = (int*)alloc((size_t)NT * 4);
  int* bsum    = (int*)alloc((size_t)1024 * 4);
  int* bbase   = (int*)alloc((size_t)1024 * 4);
  unsigned int* bits = (unsigned int*)alloc((size_t)NBITS_W * 4);
  int* rank    = (int*)alloc((size_t)N_CLAIM * 4);
  int* list    = (int*)alloc((size_t)BATCH * 4);
  int* nu      = (int*)alloc(256);
  int* col     = (int*)alloc((size_t)4 * NEDGE * 4);
  unsigned short* xb_c  = (unsigned short*)alloc((size_t)N_CLAIM    * F * 2);
  unsigned short* xb_e  = (unsigned short*)alloc((size_t)N_ENTITY   * F * 2);
  unsigned short* xb_v  = (unsigned short*)alloc((size_t)N_EVIDENCE * F * 2);
  unsigned short* mean0 = (unsigned short*)alloc((size_t)BATCH * F * 2);   // compacted
  unsigned short* mean1 = (unsigned short*)alloc((size_t)BATCH * F * 2);   // compacted
  unsigned short* h1c   = (unsigned short*)alloc((size_t)BATCH * F * 2);   // compacted
  unsigned short* h1e   = (unsigned short*)alloc((size_t)N_ENTITY   * F * 2);
  unsigned short* h1v   = (unsigned short*)alloc((size_t)N_EVIDENCE * F * 2);
  unsigned short* mean2 = (unsigned short*)alloc((size_t)N_ENTITY   * F * 2);
  unsigned short* mean3 = (unsigned short*)alloc((size_t)N_EVIDENCE * F * 2);
  unsigned short* h2c   = mean2;   // mean2 dead after entity GEMM; reuse for layer-2 output

  hipMemsetAsync(bits, 0, (size_t)NBITS_W * 4, stream);
  hipMemsetAsync(nu, 0, 4, stream);
  hipMemsetAsync(deg, 0, (size_t)NT * 4, stream);

  k_mark<<<(BATCH + 255) / 256, 256, 0, stream>>>(cbi, bits);
  k_rank<<<(N_CLAIM + 255) / 256, 256, 0, stream>>>(bits, rank, list, nu);
  k_cast<<<(N_CLAIM    * F / 4 + 255) / 256, 256, 0, stream>>>(x_c, xb_c, N_CLAIM    * F / 4);
  k_cast<<<(N_ENTITY   * F / 4 + 255) / 256, 256, 0, stream>>>(x_e, xb_e, N_ENTITY   * F / 4);
  k_cast<<<(N_EVIDENCE * F / 4 + 255) / 256, 256, 0, stream>>>(x_v, xb_v, N_EVIDENCE * F / 4);

  // CSR build: degree -> scan -> fill
  k_deg <<<(4 * EQ4 + 255) / 256, 256, 0, stream>>>(ei, bits, deg);
  k_s1  <<<NSCAN, 1024, 0, stream>>>(deg, bsum);
  k_s2  <<<1, 1024, 0, stream>>>(bsum, bbase, R);
  k_s3  <<<NSCAN, 1024, 0, stream>>>(deg, bbase, R, cur);
  k_fill<<<(4 * EQ4 + 255) / 256, 256, 0, stream>>>(ei, bits, cur, col);

  // ---- layer 1 aggregation ----
  k_agg<<<(2 * BATCH + 15) / 16, 256, 0, stream>>>(
      xb_e, xb_v, R, col, mean0, mean1, list, nu, 0, N_CLAIM, 0, 0);
  k_agg<<<(N_ENTITY + N_EVIDENCE + 15) / 16, 256, 0, stream>>>(
      xb_c, xb_c, R, col, mean2, mean3, nullptr, nullptr,
      2 * N_CLAIM, 2 * N_CLAIM + N_ENTITY, N_ENTITY, N_ENTITY + N_EVIDENCE);

  // ---- layer 1 transforms ----
  k_gemm<<<(BATCH + 63) / 64, 256, 0, stream>>>(mean0, mean1, xb_c, xb_c,
        Wl1, Wl1 + 4096, Wr1, Wr1 + 4096, bl1, bl1 + 64, h1c,
        list, 0b1100, nu, 0, 4, 1);
  k_gemm<<<(N_ENTITY + 63) / 64, 256, 0, stream>>>(mean2, xb_e, nullptr, nullptr,
        Wl1 + 2 * 4096, Wr1 + 2 * 4096, nullptr, nullptr, bl1 + 128, nullptr, h1e,
        nullptr, 0, nullptr, N_ENTITY, 2, 1);
  k_gemm<<<(N_EVIDENCE + 63) / 64, 256, 0, stream>>>(mean3, xb_v, nullptr, nullptr,
        Wl1 + 3 * 4096, Wr1 + 3 * 4096, nullptr, nullptr, bl1 + 192, nullptr, h1v,
        nullptr, 0, nullptr, N_EVIDENCE, 2, 1);

  // ---- layer 2: claims only, compacted ----
  k_agg<<<(2 * BATCH + 15) / 16, 256, 0, stream>>>(
      h1e, h1v, R, col, mean0, mean1, list, nu, 0, N_CLAIM, 0, 0);
  k_gemm<<<(BATCH + 63) / 64, 256, 0, stream>>>(mean0, mean1, h1c, h1c,
        Wl2, Wl2 + 4096, Wr2, Wr2 + 4096, bl2, bl2 + 64, h2c,
        nullptr, 0, nu, 0, 4, 0);

  // ---- classifier ----
  k_out<<<(BATCH * 64 + 255) / 256, 256, 0, stream>>>(h2c, cbi, rank, Wc, bc, out);
}

// Round 3
// 583.709 us; speedup vs baseline: 1.9242x; 1.9242x over previous
//
#include <hip/hip_runtime.h>
#include <hip/hip_bf16.h>
#include <stdint.h>

#define N_CLAIM    100000
#define N_ENTITY   200000
#define N_EVIDENCE 150000
#define NEDGE      2000000
#define F          64
#define NT         550000      // concat dst: t0 claim [0,100K) t1 claim [100K,200K) t2 ent [200K,400K) t3 evid [400K,550K)
#define BATCH      50000

#define BSH   10
#define NBKT  538
#define CAP   24576
#define B3_BLOCKS 2000
#define B3_BPT    500          // blocks per edge type (uniform type per block)
#define B3_CHUNK  4000         // 500*4000 = 2,000,000 edges per type
#define B3_ITER   16           // 16*256 = 4096 >= 4000 (iter 15 partial)
#define NBITS_W   3136         // ceil(100000/32) words for claim bitmask

static __device__ __forceinline__ float b2f(unsigned short u){
  return __uint_as_float(((unsigned int)u) << 16);
}
static __device__ __forceinline__ unsigned short f2b(float f){
  unsigned int x = __float_as_uint(f);
  x += 0x7fffu + ((x >> 16) & 1u);   // RNE
  return (unsigned short)(x >> 16);
}

// ---------------- fp32 -> bf16 cast: all three feature arrays in one launch ----------------
#define NC4 (N_CLAIM * F / 4)
#define NE4 (N_ENTITY * F / 4)
#define NV4 (N_EVIDENCE * F / 4)
__global__ void k_cast3(const float* __restrict__ a, const float* __restrict__ b,
                        const float* __restrict__ c,
                        unsigned short* __restrict__ oa, unsigned short* __restrict__ ob,
                        unsigned short* __restrict__ oc){
  int i = blockIdx.x * blockDim.x + threadIdx.x;
  const float* in; unsigned short* out; int j;
  if (i < NC4){ in = a; out = oa; j = i; }
  else if (i < NC4 + NE4){ in = b; out = ob; j = i - NC4; }
  else if (i < NC4 + NE4 + NV4){ in = c; out = oc; j = i - NC4 - NE4; }
  else return;
  float4 v = ((const float4*)in)[j];
  ushort4 o;
  o.x = f2b(v.x); o.y = f2b(v.y); o.z = f2b(v.z); o.w = f2b(v.w);
  ((ushort4*)out)[j] = o;
}

// ---------------- used-claim bitmask + compaction ----------------
__global__ void k_mark(const int* __restrict__ cbi, unsigned int* __restrict__ bits){
  int i = blockIdx.x * blockDim.x + threadIdx.x;
  if (i < BATCH){
    int c = cbi[i];
    atomicOr(&bits[c >> 5], 1u << (c & 31));
  }
}
__global__ void k_rank(const unsigned int* __restrict__ bits, int* __restrict__ rank,
                       int* __restrict__ list, int* __restrict__ nu){
  int i = blockIdx.x * blockDim.x + threadIdx.x;
  if (i < N_CLAIM && ((bits[i >> 5] >> (i & 31)) & 1u)){
    int r = atomicAdd(nu, 1);
    rank[i] = r;
    list[r] = i;
  }
}

// ---------------- CSR build: partitioned counting sort ----------------
__global__ void k_init(int* __restrict__ cursor){
  int i = blockIdx.x * blockDim.x + threadIdx.x;
  if (i < NBKT) cursor[i] = i * CAP;
}

// Phase-separated, register-resident bucket scatter.
// A: 16 coalesced dst loads + bitmask filter (16-deep MLP, no stores in flight)
// B: LDS histogram; one global atomic per touched bucket to reserve space
// C: 16 coalesced src loads (issued before ANY store)
// D: LDS rank + 16 scattered stores LAST (store acks never block a load chain)
__global__ __launch_bounds__(256) void k_bscatter(const int* __restrict__ ei,
                                                  const unsigned int* __restrict__ bits,
                                                  int* __restrict__ cursor,
                                                  unsigned int* __restrict__ pairs){
  __shared__ int hcnt[NBKT];
  __shared__ int hpos[NBKT];
  const int toff[4] = {0, N_CLAIM, 2*N_CLAIM, 2*N_CLAIM + N_ENTITY};
  int tid = threadIdx.x;
  int bpt = blockIdx.x / B3_BPT;                     // edge type, uniform per block
  int e0  = (blockIdx.x - bpt * B3_BPT) * B3_CHUNK;  // base edge within type
  int off_t = toff[bpt];
  bool isclaim = (bpt < 2);
  const int* dstp = ei + (size_t)bpt * 2 * NEDGE + NEDGE + e0;
  const int* srcp = ei + (size_t)bpt * 2 * NEDGE + e0;
  for (int b = tid; b < NBKT; b += 256) hcnt[b] = 0;
  __syncthreads();
  unsigned int v[B3_ITER];
  #pragma unroll
  for (int i = 0; i < B3_ITER; ++i){
    int li = i * 256 + tid;
    v[i] = 0xFFFFFFFFu;
    if (li < B3_CHUNK){
      int dst = dstp[li];
      if (!isclaim || ((bits[dst >> 5] >> (dst & 31)) & 1u))
        v[i] = (unsigned int)(dst + off_t);
    }
  }
  #pragma unroll
  for (int i = 0; i < B3_ITER; ++i)
    if (v[i] != 0xFFFFFFFFu) atomicAdd(&hcnt[v[i] >> BSH], 1);
  __syncthreads();
  for (int b = tid; b < NBKT; b += 256){
    int c = hcnt[b];
    hpos[b] = c ? atomicAdd(&cursor[b], c) : 0;
  }
  __syncthreads();
  int s[B3_ITER];
  #pragma unroll
  for (int i = 0; i < B3_ITER; ++i){
    int li = i * 256 + tid;
    s[i] = (li < B3_CHUNK) ? srcp[li] : 0;
  }
  #pragma unroll
  for (int i = 0; i < B3_ITER; ++i){
    if (v[i] != 0xFFFFFFFFu){
      int o = atomicAdd(&hpos[v[i] >> BSH], 1);
      pairs[o] = ((v[i] & ((1u << BSH) - 1)) << 18) | (unsigned int)s[i];
    }
  }
}

__global__ void k_bscan(const int* __restrict__ cursor, int* __restrict__ colBase,
                        int* __restrict__ R){
  __shared__ int s[1024];
  int tid = threadIdx.x;
  int c = (tid < NBKT) ? (cursor[tid] - tid * CAP) : 0;
  s[tid] = c;
  __syncthreads();
  for (int off = 1; off < 1024; off <<= 1){
    int t = (tid >= off) ? s[tid - off] : 0;
    __syncthreads();
    s[tid] += t;
    __syncthreads();
  }
  if (tid < NBKT) colBase[tid] = s[tid] - c;
  if (tid == 1023) R[NT] = s[1023];
}

// 1024 threads: 1 node/thread, 16 waves/block
__global__ __launch_bounds__(1024) void k_csr(const unsigned int* __restrict__ pairs,
                                              const int* __restrict__ cursor,
                                              const int* __restrict__ colBase,
                                              int* __restrict__ R, int* __restrict__ col){
  __shared__ int h[1024];
  __shared__ int s[1024];
  int b = blockIdx.x, tid = threadIdx.x;
  int cnt   = cursor[b] - b * CAP;
  int base  = colBase[b];
  int pbase = b * CAP;
  h[tid] = 0;
  __syncthreads();
  for (int i = tid; i < cnt; i += 1024)
    atomicAdd(&h[pairs[pbase + i] >> 18], 1);
  __syncthreads();
  int c = h[tid];
  s[tid] = c;
  __syncthreads();
  for (int off = 1; off < 1024; off <<= 1){
    int t = (tid >= off) ? s[tid - off] : 0;
    __syncthreads();
    s[tid] += t;
    __syncthreads();
  }
  int ex = s[tid] - c;          // exclusive prefix within bucket
  h[tid] = ex;
  int n = (b << BSH) + tid;
  if (n < NT) R[n] = base + ex;
  __syncthreads();
  for (int i = tid; i < cnt; i += 1024){
    unsigned int p = pairs[pbase + i];
    int r = atomicAdd(&h[p >> 18], 1);
    col[base + r] = (int)(p & 0x3FFFFu);
  }
}

// ---- mean aggregation: 4 dst rows per wave, 16 lanes x 8B per row, no cross-row reduce ----
__global__ __launch_bounds__(256) void k_agg(const unsigned short* __restrict__ X0,
                                             const unsigned short* __restrict__ X1,
                                             const int* __restrict__ R,
                                             const int* __restrict__ col,
                                             unsigned short* __restrict__ M0,
                                             unsigned short* __restrict__ M1,
                                             const int* __restrict__ list,
                                             const int* __restrict__ nu_ptr,
                                             int RbA, int RbB, int nd0_param, int njobs_param){
  int tid  = threadIdx.x;
  int lane = tid & 63;
  int g    = lane >> 4;          // row group 0..3
  int fl   = lane & 15;          // feature slot: features [4fl, 4fl+4)
  int wv   = (int)blockIdx.x * 4 + (tid >> 6);
  int nu     = list ? *nu_ptr : 0;
  int njobs  = list ? 2 * nu : njobs_param;
  int nd0    = list ? nu : nd0_param;
  int j = wv * 4 + g;
  bool active = j < njobs;
  int sub_t = 0, idx = 0, row = 0, node = 0;
  if (active){
    sub_t = (j >= nd0) ? 1 : 0;
    idx = j - (sub_t ? nd0 : 0);
    row = list ? list[idx] : idx;
    node = (sub_t ? RbB : RbA) + row;
  }
  const unsigned short* X = sub_t ? X1 : X0;
  unsigned short* Mo = sub_t ? M1 : M0;
  int rbeg = 0, rend = 0;
  if (active){ rbeg = R[node]; rend = R[node + 1]; }
  int deg = rend - rbeg;
  float4 acc = {0.f, 0.f, 0.f, 0.f};
  for (int p = rbeg; p < rend; p += 8){
    int nb = rend - p; if (nb > 8) nb = 8;
    int cid = 0;
    if (fl < nb) cid = col[p + fl];      // 1 coalesced id prefetch per 8 edges
    #pragma unroll
    for (int k = 0; k < 8; ++k){
      int c = __shfl(cid, (g << 4) + k, 64);
      if (k < nb){
        uint2 d = *(const uint2*)(X + c * F + fl * 4);
        acc.x += __uint_as_float(d.x << 16);
        acc.y += __uint_as_float(d.x & 0xffff0000u);
        acc.z += __uint_as_float(d.y << 16);
        acc.w += __uint_as_float(d.y & 0xffff0000u);
      }
    }
  }
  if (active){
    float r = deg ? (1.0f / (float)deg) : 0.f;
    ushort4 o;
    o.x = f2b(acc.x * r); o.y = f2b(acc.y * r);
    o.z = f2b(acc.z * r); o.w = f2b(acc.w * r);
    *(ushort4*)(Mo + (long long)idx * F + fl * 4) = o;
  }
}

// ---- fused multi-source GEMM: H = act(sum_j Aj@Wj + bias) ----
typedef __bf16 bf16x8 __attribute__((ext_vector_type(8)));
typedef float  f32x4  __attribute__((ext_vector_type(4)));
#define WT_STRIDE 72

__global__ __launch_bounds__(256) void k_gemm(
    const unsigned short* __restrict__ A0, const unsigned short* __restrict__ A1,
    const unsigned short* __restrict__ A2, const unsigned short* __restrict__ A3,
    const float* __restrict__ W0, const float* __restrict__ W1,
    const float* __restrict__ W2, const float* __restrict__ W3,
    const float* __restrict__ b0, const float* __restrict__ b1,
    unsigned short* __restrict__ Hout,
    const int* __restrict__ Alist, int amask,
    const int* __restrict__ Mptr, int Mparam, int ns, int relu)
{
  int M = Mptr ? *Mptr : Mparam;
  if ((int)blockIdx.x * 64 >= M) return;     // block-uniform early exit
  __shared__ __align__(16) unsigned short WT[4 * 64 * WT_STRIDE];
  const float* Ws[4] = {W0, W1, W2, W3};
  const unsigned short* As[4] = {A0, A1, A2, A3};
  int tid = threadIdx.x;
  for (int j = 0; j < ns; j++){
    const float* Wj = Ws[j];
    #pragma unroll
    for (int q = 0; q < 16; q++){
      int idx = q * 256 + tid;
      int k = idx >> 6, n = idx & 63;
      WT[j * 64 * WT_STRIDE + n * WT_STRIDE + k] = f2b(Wj[idx]);
    }
  }
  __syncthreads();
  int wave = tid >> 6, lane = tid & 63;
  int quad = lane >> 4, l16 = lane & 15;
  int m0 = blockIdx.x * 64 + wave * 16;
  int arow = m0 + l16; if (arow >= M) arow = M - 1;
  int arows[4];
  #pragma unroll
  for (int j = 0; j < 4; j++)
    arows[j] = ((amask >> j) & 1) ? Alist[arow] : arow;
  f32x4 z = {0.f, 0.f, 0.f, 0.f};
  f32x4 acc[4] = {z, z, z, z};
  for (int j = 0; j < ns; j++){
    const unsigned short* Aj = As[j];
    #pragma unroll
    for (int kk = 0; kk < 64; kk += 32){
      bf16x8 af = *(const bf16x8*)(Aj + (long long)arows[j] * F + kk + quad * 8);
      #pragma unroll
      for (int c = 0; c < 4; c++){
        const unsigned short* bp = &WT[j * 64 * WT_STRIDE + (c * 16 + l16) * WT_STRIDE + kk + quad * 8];
        bf16x8 bfr = *(const bf16x8*)bp;
        acc[c] = __builtin_amdgcn_mfma_f32_16x16x32_bf16(af, bfr, acc[c], 0, 0, 0);
      }
    }
  }
  #pragma unroll
  for (int c = 0; c < 4; c++){
    int n = c * 16 + l16;
    float bv = b0[n] + (b1 ? b1[n] : 0.f);
    #pragma unroll
    for (int r = 0; r < 4; r++){
      int row = m0 + quad * 4 + r;
      if (row < M){
        float v = acc[c][r] + bv;
        if (relu) v = fmaxf(v, 0.f);
        Hout[(long long)row * F + n] = f2b(v);
      }
    }
  }
}

// ---------------- final classifier: wave per batch row; fp32 out ----------------
__global__ void k_out(const unsigned short* __restrict__ h2,
                      const int* __restrict__ cbi,
                      const int* __restrict__ rank,
                      const float* __restrict__ Wc,
                      const float* __restrict__ bcp,
                      float* __restrict__ out){
  int w = (int)(((unsigned)blockIdx.x * blockDim.x + threadIdx.x) >> 6);
  int lane = threadIdx.x & 63;
  if (w >= BATCH) return;
  int rk = rank[cbi[w]];
  float v = b2f(h2[(long long)rk * F + lane]);
  float p0 = v * Wc[lane * 2];
  float p1 = v * Wc[lane * 2 + 1];
  for (int off = 32; off; off >>= 1){
    p0 += __shfl_xor(p0, off, 64);
    p1 += __shfl_xor(p1, off, 64);
  }
  if (lane == 0){
    out[2 * w]     = p0 + bcp[0];
    out[2 * w + 1] = p1 + bcp[1];
  }
}

extern "C" void kernel_launch(void* const* d_in, const int* in_sizes, int n_in,
                              void* d_out, int out_size, void* d_ws, size_t ws_size,
                              hipStream_t stream)
{
  const float* x_c = (const float*)d_in[0];
  const float* x_e = (const float*)d_in[1];
  const float* x_v = (const float*)d_in[2];
  const int*   ei  = (const int*)d_in[3];
  const int*   cbi = (const int*)d_in[4];
  const float* Wl1 = (const float*)d_in[5];
  const float* bl1 = (const float*)d_in[6];
  const float* Wr1 = (const float*)d_in[7];
  const float* Wl2 = (const float*)d_in[8];
  const float* bl2 = (const float*)d_in[9];
  const float* Wr2 = (const float*)d_in[10];
  const float* Wc  = (const float*)d_in[11];
  const float* bc  = (const float*)d_in[12];
  float* out = (float*)d_out;

  char* ws = (char*)d_ws;
  size_t off = 0;
  auto alloc = [&](size_t bytes) -> char* {
    char* p = ws + off;
    off += (bytes + 255) & ~(size_t)255;
    return p;
  };
  int* R       = (int*)alloc((size_t)(NT + 1) * 4);
  int* cursor  = (int*)alloc((size_t)NBKT * 4);
  int* colBase = (int*)alloc((size_t)NBKT * 4);
  unsigned int* bits = (unsigned int*)alloc((size_t)NBITS_W * 4);
  int* rank    = (int*)alloc((size_t)N_CLAIM * 4);
  int* list    = (int*)alloc((size_t)BATCH * 4);
  int* nu      = (int*)alloc(256);
  int* col     = (int*)alloc((size_t)4 * NEDGE * 4);
  unsigned int* pairs = (unsigned int*)alloc((size_t)NBKT * CAP * 4);   // dead after k_csr
  unsigned short* xb_c  = (unsigned short*)alloc((size_t)N_CLAIM    * F * 2);
  unsigned short* xb_e  = (unsigned short*)alloc((size_t)N_ENTITY   * F * 2);
  unsigned short* xb_v  = (unsigned short*)alloc((size_t)N_EVIDENCE * F * 2);
  unsigned short* mean0 = (unsigned short*)alloc((size_t)BATCH * F * 2);   // compacted
  unsigned short* mean1 = (unsigned short*)alloc((size_t)BATCH * F * 2);   // compacted
  unsigned short* h1c   = (unsigned short*)alloc((size_t)BATCH * F * 2);   // compacted
  unsigned short* h1e   = (unsigned short*)alloc((size_t)N_ENTITY   * F * 2);
  unsigned short* h1v   = (unsigned short*)alloc((size_t)N_EVIDENCE * F * 2);
  unsigned short* mean2 = (unsigned short*)pairs;   // alias dead pairs region
  unsigned short* mean3 = (unsigned short*)((char*)pairs + (size_t)N_ENTITY * F * 2);
  unsigned short* h2c   = mean2;                    // compacted; mean2 dead after entity GEMM

  hipMemsetAsync(bits, 0, (size_t)NBITS_W * 4, stream);
  hipMemsetAsync(nu, 0, 4, stream);

  k_mark<<<(BATCH + 255) / 256, 256, 0, stream>>>(cbi, bits);
  k_rank<<<(N_CLAIM + 255) / 256, 256, 0, stream>>>(bits, rank, list, nu);
  k_cast3<<<(NC4 + NE4 + NV4 + 255) / 256, 256, 0, stream>>>(x_c, x_e, x_v, xb_c, xb_e, xb_v);

  k_init<<<(NBKT + 255) / 256, 256, 0, stream>>>(cursor);
  k_bscatter<<<B3_BLOCKS, 256, 0, stream>>>(ei, bits, cursor, pairs);
  k_bscan<<<1, 1024, 0, stream>>>(cursor, colBase, R);
  k_csr<<<NBKT, 1024, 0, stream>>>(pairs, cursor, colBase, R, col);

  // ---- layer 1 aggregation ----
  k_agg<<<(2 * BATCH + 15) / 16, 256, 0, stream>>>(
      xb_e, xb_v, R, col, mean0, mean1, list, nu, 0, N_CLAIM, 0, 0);
  k_agg<<<(N_ENTITY + N_EVIDENCE + 15) / 16, 256, 0, stream>>>(
      xb_c, xb_c, R, col, mean2, mean3, nullptr, nullptr,
      2 * N_CLAIM, 2 * N_CLAIM + N_ENTITY, N_ENTITY, N_ENTITY + N_EVIDENCE);

  // ---- layer 1 transforms ----
  k_gemm<<<(BATCH + 63) / 64, 256, 0, stream>>>(mean0, mean1, xb_c, xb_c,
        Wl1, Wl1 + 4096, Wr1, Wr1 + 4096, bl1, bl1 + 64, h1c,
        list, 0b1100, nu, 0, 4, 1);
  k_gemm<<<(N_ENTITY + 63) / 64, 256, 0, stream>>>(mean2, xb_e, nullptr, nullptr,
        Wl1 + 2 * 4096, Wr1 + 2 * 4096, nullptr, nullptr, bl1 + 128, nullptr, h1e,
        nullptr, 0, nullptr, N_ENTITY, 2, 1);
  k_gemm<<<(N_EVIDENCE + 63) / 64, 256, 0, stream>>>(mean3, xb_v, nullptr, nullptr,
        Wl1 + 3 * 4096, Wr1 + 3 * 4096, nullptr, nullptr, bl1 + 192, nullptr, h1v,
        nullptr, 0, nullptr, N_EVIDENCE, 2, 1);

  // ---- layer 2: claims only, compacted ----
  k_agg<<<(2 * BATCH + 15) / 16, 256, 0, stream>>>(
      h1e, h1v, R, col, mean0, mean1, list, nu, 0, N_CLAIM, 0, 0);
  k_gemm<<<(BATCH + 63) / 64, 256, 0, stream>>>(mean0, mean1, h1c, h1c,
        Wl2, Wl2 + 4096, Wr2, Wr2 + 4096, bl2, bl2 + 64, h2c,
        nullptr, 0, nu, 0, 4, 0);

  // ---- classifier ----
  k_out<<<(BATCH * 64 + 255) / 256, 256, 0, stream>>>(h2c, cbi, rank, Wc, bc, out);
}

// Round 4
// 549.987 us; speedup vs baseline: 2.0422x; 1.0613x over previous
//
#include <hip/hip_runtime.h>
#include <hip/hip_bf16.h>
#include <stdint.h>

#define N_CLAIM    100000
#define N_ENTITY   200000
#define N_EVIDENCE 150000
#define NEDGE      2000000
#define F          64
#define NT         550000      // concat dst: t0 claim [0,100K) t1 claim [100K,200K) t2 ent [200K,400K) t3 evid [400K,550K)
#define BATCH      50000

#define BSH   10
#define NBKT  538
#define CAP   24576
#define B3_BLOCKS 2000
#define B3_BPT    500          // blocks per edge type (uniform type per block)
#define B3_CHUNK  4000         // 500*4000 = 2,000,000 edges per type
#define B3_ITER   16           // 16*256 = 4096 >= 4000 (iter 15 partial)
#define NBITS_W   3136         // ceil(100000/32) words for claim bitmask

static __device__ __forceinline__ float b2f(unsigned short u){
  return __uint_as_float(((unsigned int)u) << 16);
}
static __device__ __forceinline__ unsigned short f2b(float f){
  unsigned int x = __float_as_uint(f);
  x += 0x7fffu + ((x >> 16) & 1u);   // RNE
  return (unsigned short)(x >> 16);
}

typedef float f32x2v __attribute__((ext_vector_type(2)));

static __device__ __forceinline__ f32x2v pk_add(f32x2v a, f32x2v b){
  f32x2v d;
  asm("v_pk_add_f32 %0, %1, %2" : "=v"(d) : "v"(a), "v"(b));
  return d;
}
// unpack one dword (2 bf16) -> f32x2 {even feat, odd feat}
static __device__ __forceinline__ f32x2v unp(unsigned int w){
  f32x2v r;
  r.x = __uint_as_float(w << 16);
  r.y = __uint_as_float(w & 0xffff0000u);
  return r;
}

// ---------------- fp32 -> bf16 cast: all three feature arrays in one launch ----------------
#define NC4 (N_CLAIM * F / 4)
#define NE4 (N_ENTITY * F / 4)
#define NV4 (N_EVIDENCE * F / 4)
__global__ void k_cast3(const float* __restrict__ a, const float* __restrict__ b,
                        const float* __restrict__ c,
                        unsigned short* __restrict__ oa, unsigned short* __restrict__ ob,
                        unsigned short* __restrict__ oc){
  int i = blockIdx.x * blockDim.x + threadIdx.x;
  const float* in; unsigned short* out; int j;
  if (i < NC4){ in = a; out = oa; j = i; }
  else if (i < NC4 + NE4){ in = b; out = ob; j = i - NC4; }
  else if (i < NC4 + NE4 + NV4){ in = c; out = oc; j = i - NC4 - NE4; }
  else return;
  float4 v = ((const float4*)in)[j];
  ushort4 o;
  o.x = f2b(v.x); o.y = f2b(v.y); o.z = f2b(v.z); o.w = f2b(v.w);
  ((ushort4*)out)[j] = o;
}

// ---------------- used-claim bitmask + compaction ----------------
__global__ void k_mark(const int* __restrict__ cbi, unsigned int* __restrict__ bits){
  int i = blockIdx.x * blockDim.x + threadIdx.x;
  if (i < BATCH){
    int c = cbi[i];
    atomicOr(&bits[c >> 5], 1u << (c & 31));
  }
}
__global__ void k_rank(const unsigned int* __restrict__ bits, int* __restrict__ rank,
                       int* __restrict__ list, int* __restrict__ nu){
  int i = blockIdx.x * blockDim.x + threadIdx.x;
  if (i < N_CLAIM && ((bits[i >> 5] >> (i & 31)) & 1u)){
    int r = atomicAdd(nu, 1);
    rank[i] = r;
    list[r] = i;
  }
}

// ---------------- CSR build: partitioned counting sort ----------------
__global__ void k_init(int* __restrict__ cursor){
  int i = blockIdx.x * blockDim.x + threadIdx.x;
  if (i < NBKT) cursor[i] = i * CAP;
}

// Phase-separated, register-resident bucket scatter.
__global__ __launch_bounds__(256) void k_bscatter(const int* __restrict__ ei,
                                                  const unsigned int* __restrict__ bits,
                                                  int* __restrict__ cursor,
                                                  unsigned int* __restrict__ pairs){
  __shared__ int hcnt[NBKT];
  __shared__ int hpos[NBKT];
  const int toff[4] = {0, N_CLAIM, 2*N_CLAIM, 2*N_CLAIM + N_ENTITY};
  int tid = threadIdx.x;
  int bpt = blockIdx.x / B3_BPT;                     // edge type, uniform per block
  int e0  = (blockIdx.x - bpt * B3_BPT) * B3_CHUNK;  // base edge within type
  int off_t = toff[bpt];
  bool isclaim = (bpt < 2);
  const int* dstp = ei + (size_t)bpt * 2 * NEDGE + NEDGE + e0;
  const int* srcp = ei + (size_t)bpt * 2 * NEDGE + e0;
  for (int b = tid; b < NBKT; b += 256) hcnt[b] = 0;
  __syncthreads();
  unsigned int v[B3_ITER];
  #pragma unroll
  for (int i = 0; i < B3_ITER; ++i){
    int li = i * 256 + tid;
    v[i] = 0xFFFFFFFFu;
    if (li < B3_CHUNK){
      int dst = dstp[li];
      if (!isclaim || ((bits[dst >> 5] >> (dst & 31)) & 1u))
        v[i] = (unsigned int)(dst + off_t);
    }
  }
  #pragma unroll
  for (int i = 0; i < B3_ITER; ++i)
    if (v[i] != 0xFFFFFFFFu) atomicAdd(&hcnt[v[i] >> BSH], 1);
  __syncthreads();
  for (int b = tid; b < NBKT; b += 256){
    int c = hcnt[b];
    hpos[b] = c ? atomicAdd(&cursor[b], c) : 0;
  }
  __syncthreads();
  int s[B3_ITER];
  #pragma unroll
  for (int i = 0; i < B3_ITER; ++i){
    int li = i * 256 + tid;
    s[i] = (li < B3_CHUNK) ? srcp[li] : 0;
  }
  #pragma unroll
  for (int i = 0; i < B3_ITER; ++i){
    if (v[i] != 0xFFFFFFFFu){
      int o = atomicAdd(&hpos[v[i] >> BSH], 1);
      pairs[o] = ((v[i] & ((1u << BSH) - 1)) << 18) | (unsigned int)s[i];
    }
  }
}

__global__ void k_bscan(const int* __restrict__ cursor, int* __restrict__ colBase,
                        int* __restrict__ R){
  __shared__ int s[1024];
  int tid = threadIdx.x;
  int c = (tid < NBKT) ? (cursor[tid] - tid * CAP) : 0;
  s[tid] = c;
  __syncthreads();
  for (int off = 1; off < 1024; off <<= 1){
    int t = (tid >= off) ? s[tid - off] : 0;
    __syncthreads();
    s[tid] += t;
    __syncthreads();
  }
  if (tid < NBKT) colBase[tid] = s[tid] - c;
  if (tid == 1023) R[NT] = s[1023];
}

// 1024 threads: 1 node/thread, 16 waves/block
__global__ __launch_bounds__(1024) void k_csr(const unsigned int* __restrict__ pairs,
                                              const int* __restrict__ cursor,
                                              const int* __restrict__ colBase,
                                              int* __restrict__ R, int* __restrict__ col){
  __shared__ int h[1024];
  __shared__ int s[1024];
  int b = blockIdx.x, tid = threadIdx.x;
  int cnt   = cursor[b] - b * CAP;
  int base  = colBase[b];
  int pbase = b * CAP;
  h[tid] = 0;
  __syncthreads();
  for (int i = tid; i < cnt; i += 1024)
    atomicAdd(&h[pairs[pbase + i] >> 18], 1);
  __syncthreads();
  int c = h[tid];
  s[tid] = c;
  __syncthreads();
  for (int off = 1; off < 1024; off <<= 1){
    int t = (tid >= off) ? s[tid - off] : 0;
    __syncthreads();
    s[tid] += t;
    __syncthreads();
  }
  int ex = s[tid] - c;          // exclusive prefix within bucket
  h[tid] = ex;
  int n = (b << BSH) + tid;
  if (n < NT) R[n] = base + ex;
  __syncthreads();
  for (int i = tid; i < cnt; i += 1024){
    unsigned int p = pairs[pbase + i];
    int r = atomicAdd(&h[p >> 18], 1);
    col[base + r] = (int)(p & 0x3FFFFu);
  }
}

// ---- mean aggregation: 8 dst rows per wave, 8 lanes x 16B per row ----
// uint4 gathers (half the load/shfl instrs of uint2), v_pk_add_f32 accumulate
// (3 VALU per dword vs 8), cid prefetched one chunk ahead.
__global__ __launch_bounds__(256) void k_agg(const unsigned short* __restrict__ X0,
                                             const unsigned short* __restrict__ X1,
                                             const int* __restrict__ R,
                                             const int* __restrict__ col,
                                             unsigned short* __restrict__ M0,
                                             unsigned short* __restrict__ M1,
                                             const int* __restrict__ list,
                                             const int* __restrict__ nu_ptr,
                                             int RbA, int RbB, int nd0_param, int njobs_param){
  int tid  = threadIdx.x;
  int lane = tid & 63;
  int g    = lane >> 3;          // row group 0..7
  int fl   = lane & 7;           // feature slot: features [8fl, 8fl+8)
  int wv   = (int)blockIdx.x * 4 + (tid >> 6);
  int nu     = list ? *nu_ptr : 0;
  int njobs  = list ? 2 * nu : njobs_param;
  int nd0    = list ? nu : nd0_param;
  int j = wv * 8 + g;
  bool active = j < njobs;
  int sub_t = 0, idx = 0, row = 0, node = 0;
  if (active){
    sub_t = (j >= nd0) ? 1 : 0;
    idx = j - (sub_t ? nd0 : 0);
    row = list ? list[idx] : idx;
    node = (sub_t ? RbB : RbA) + row;
  }
  const unsigned short* X = sub_t ? X1 : X0;
  unsigned short* Mo = sub_t ? M1 : M0;
  int rbeg = 0, rend = 0;
  if (active){ rbeg = R[node]; rend = R[node + 1]; }
  int deg = rend - rbeg;
  f32x2v z = {0.f, 0.f};
  f32x2v acc[4] = {z, z, z, z};
  int cid = 0;
  if (active && fl < deg) cid = col[rbeg + fl];   // first chunk ids (fl<8 implicit)
  for (int p = rbeg; p < rend; p += 8){
    int nb = rend - p; if (nb > 8) nb = 8;
    int cc = cid;
    int pn = p + 8;
    int rem = rend - pn;
    if (rem > 0 && fl < rem) cid = col[pn + fl];  // prefetch next chunk ids
    #pragma unroll
    for (int k = 0; k < 8; ++k){
      int c = __shfl(cc, (g << 3) + k, 64);
      if (k < nb){
        uint4 d = *(const uint4*)(X + (long long)c * F + fl * 8);
        acc[0] = pk_add(acc[0], unp(d.x));
        acc[1] = pk_add(acc[1], unp(d.y));
        acc[2] = pk_add(acc[2], unp(d.z));
        acc[3] = pk_add(acc[3], unp(d.w));
      }
    }
  }
  if (active){
    float r = deg ? (1.0f / (float)deg) : 0.f;
    uint4 o;
    o.x = ((unsigned int)f2b(acc[0].y * r) << 16) | f2b(acc[0].x * r);
    o.y = ((unsigned int)f2b(acc[1].y * r) << 16) | f2b(acc[1].x * r);
    o.z = ((unsigned int)f2b(acc[2].y * r) << 16) | f2b(acc[2].x * r);
    o.w = ((unsigned int)f2b(acc[3].y * r) << 16) | f2b(acc[3].x * r);
    *(uint4*)(Mo + (long long)idx * F + fl * 8) = o;
  }
}

// ---- fused multi-source GEMM: H = act(sum_j Aj@Wj + bias) ----
typedef __bf16 bf16x8 __attribute__((ext_vector_type(8)));
typedef float  f32x4  __attribute__((ext_vector_type(4)));
#define WT_STRIDE 72

__global__ __launch_bounds__(256) void k_gemm(
    const unsigned short* __restrict__ A0, const unsigned short* __restrict__ A1,
    const unsigned short* __restrict__ A2, const unsigned short* __restrict__ A3,
    const float* __restrict__ W0, const float* __restrict__ W1,
    const float* __restrict__ W2, const float* __restrict__ W3,
    const float* __restrict__ b0, const float* __restrict__ b1,
    unsigned short* __restrict__ Hout,
    const int* __restrict__ Alist, int amask,
    const int* __restrict__ Mptr, int Mparam, int ns, int relu)
{
  int M = Mptr ? *Mptr : Mparam;
  if ((int)blockIdx.x * 64 >= M) return;     // block-uniform early exit
  __shared__ __align__(16) unsigned short WT[4 * 64 * WT_STRIDE];
  const float* Ws[4] = {W0, W1, W2, W3};
  const unsigned short* As[4] = {A0, A1, A2, A3};
  int tid = threadIdx.x;
  for (int j = 0; j < ns; j++){
    const float* Wj = Ws[j];
    #pragma unroll
    for (int q = 0; q < 16; q++){
      int idx = q * 256 + tid;
      int k = idx >> 6, n = idx & 63;
      WT[j * 64 * WT_STRIDE + n * WT_STRIDE + k] = f2b(Wj[idx]);
    }
  }
  __syncthreads();
  int wave = tid >> 6, lane = tid & 63;
  int quad = lane >> 4, l16 = lane & 15;
  int m0 = blockIdx.x * 64 + wave * 16;
  int arow = m0 + l16; if (arow >= M) arow = M - 1;
  int arows[4];
  #pragma unroll
  for (int j = 0; j < 4; j++)
    arows[j] = ((amask >> j) & 1) ? Alist[arow] : arow;
  f32x4 z = {0.f, 0.f, 0.f, 0.f};
  f32x4 acc[4] = {z, z, z, z};
  for (int j = 0; j < ns; j++){
    const unsigned short* Aj = As[j];
    #pragma unroll
    for (int kk = 0; kk < 64; kk += 32){
      bf16x8 af = *(const bf16x8*)(Aj + (long long)arows[j] * F + kk + quad * 8);
      #pragma unroll
      for (int c = 0; c < 4; c++){
        const unsigned short* bp = &WT[j * 64 * WT_STRIDE + (c * 16 + l16) * WT_STRIDE + kk + quad * 8];
        bf16x8 bfr = *(const bf16x8*)bp;
        acc[c] = __builtin_amdgcn_mfma_f32_16x16x32_bf16(af, bfr, acc[c], 0, 0, 0);
      }
    }
  }
  #pragma unroll
  for (int c = 0; c < 4; c++){
    int n = c * 16 + l16;
    float bv = b0[n] + (b1 ? b1[n] : 0.f);
    #pragma unroll
    for (int r = 0; r < 4; r++){
      int row = m0 + quad * 4 + r;
      if (row < M){
        float v = acc[c][r] + bv;
        if (relu) v = fmaxf(v, 0.f);
        Hout[(long long)row * F + n] = f2b(v);
      }
    }
  }
}

// ---------------- final classifier: wave per batch row; fp32 out ----------------
__global__ void k_out(const unsigned short* __restrict__ h2,
                      const int* __restrict__ cbi,
                      const int* __restrict__ rank,
                      const float* __restrict__ Wc,
                      const float* __restrict__ bcp,
                      float* __restrict__ out){
  int w = (int)(((unsigned)blockIdx.x * blockDim.x + threadIdx.x) >> 6);
  int lane = threadIdx.x & 63;
  if (w >= BATCH) return;
  int rk = rank[cbi[w]];
  float v = b2f(h2[(long long)rk * F + lane]);
  float p0 = v * Wc[lane * 2];
  float p1 = v * Wc[lane * 2 + 1];
  for (int off = 32; off; off >>= 1){
    p0 += __shfl_xor(p0, off, 64);
    p1 += __shfl_xor(p1, off, 64);
  }
  if (lane == 0){
    out[2 * w]     = p0 + bcp[0];
    out[2 * w + 1] = p1 + bcp[1];
  }
}

extern "C" void kernel_launch(void* const* d_in, const int* in_sizes, int n_in,
                              void* d_out, int out_size, void* d_ws, size_t ws_size,
                              hipStream_t stream)
{
  const float* x_c = (const float*)d_in[0];
  const float* x_e = (const float*)d_in[1];
  const float* x_v = (const float*)d_in[2];
  const int*   ei  = (const int*)d_in[3];
  const int*   cbi = (const int*)d_in[4];
  const float* Wl1 = (const float*)d_in[5];
  const float* bl1 = (const float*)d_in[6];
  const float* Wr1 = (const float*)d_in[7];
  const float* Wl2 = (const float*)d_in[8];
  const float* bl2 = (const float*)d_in[9];
  const float* Wr2 = (const float*)d_in[10];
  const float* Wc  = (const float*)d_in[11];
  const float* bc  = (const float*)d_in[12];
  float* out = (float*)d_out;

  char* ws = (char*)d_ws;
  size_t off = 0;
  auto alloc = [&](size_t bytes) -> char* {
    char* p = ws + off;
    off += (bytes + 255) & ~(size_t)255;
    return p;
  };
  int* R       = (int*)alloc((size_t)(NT + 1) * 4);
  int* cursor  = (int*)alloc((size_t)NBKT * 4);
  int* colBase = (int*)alloc((size_t)NBKT * 4);
  unsigned int* bits = (unsigned int*)alloc((size_t)NBITS_W * 4);
  int* rank    = (int*)alloc((size_t)N_CLAIM * 4);
  int* list    = (int*)alloc((size_t)BATCH * 4);
  int* nu      = (int*)alloc(256);
  int* col     = (int*)alloc((size_t)4 * NEDGE * 4);
  unsigned int* pairs = (unsigned int*)alloc((size_t)NBKT * CAP * 4);   // dead after k_csr
  unsigned short* xb_c  = (unsigned short*)alloc((size_t)N_CLAIM    * F * 2);
  unsigned short* xb_e  = (unsigned short*)alloc((size_t)N_ENTITY   * F * 2);
  unsigned short* xb_v  = (unsigned short*)alloc((size_t)N_EVIDENCE * F * 2);
  unsigned short* mean0 = (unsigned short*)alloc((size_t)BATCH * F * 2);   // compacted
  unsigned short* mean1 = (unsigned short*)alloc((size_t)BATCH * F * 2);   // compacted
  unsigned short* h1c   = (unsigned short*)alloc((size_t)BATCH * F * 2);   // compacted
  unsigned short* h1e   = (unsigned short*)alloc((size_t)N_ENTITY   * F * 2);
  unsigned short* h1v   = (unsigned short*)alloc((size_t)N_EVIDENCE * F * 2);
  unsigned short* mean2 = (unsigned short*)pairs;   // alias dead pairs region
  unsigned short* mean3 = (unsigned short*)((char*)pairs + (size_t)N_ENTITY * F * 2);
  unsigned short* h2c   = mean2;                    // compacted; mean2 dead after entity GEMM

  hipMemsetAsync(bits, 0, (size_t)NBITS_W * 4, stream);
  hipMemsetAsync(nu, 0, 4, stream);

  k_mark<<<(BATCH + 255) / 256, 256, 0, stream>>>(cbi, bits);
  k_rank<<<(N_CLAIM + 255) / 256, 256, 0, stream>>>(bits, rank, list, nu);
  k_cast3<<<(NC4 + NE4 + NV4 + 255) / 256, 256, 0, stream>>>(x_c, x_e, x_v, xb_c, xb_e, xb_v);

  k_init<<<(NBKT + 255) / 256, 256, 0, stream>>>(cursor);
  k_bscatter<<<B3_BLOCKS, 256, 0, stream>>>(ei, bits, cursor, pairs);
  k_bscan<<<1, 1024, 0, stream>>>(cursor, colBase, R);
  k_csr<<<NBKT, 1024, 0, stream>>>(pairs, cursor, colBase, R, col);

  // ---- layer 1 aggregation ----
  k_agg<<<(2 * BATCH + 31) / 32, 256, 0, stream>>>(
      xb_e, xb_v, R, col, mean0, mean1, list, nu, 0, N_CLAIM, 0, 0);
  k_agg<<<(N_ENTITY + N_EVIDENCE + 31) / 32, 256, 0, stream>>>(
      xb_c, xb_c, R, col, mean2, mean3, nullptr, nullptr,
      2 * N_CLAIM, 2 * N_CLAIM + N_ENTITY, N_ENTITY, N_ENTITY + N_EVIDENCE);

  // ---- layer 1 transforms ----
  k_gemm<<<(BATCH + 63) / 64, 256, 0, stream>>>(mean0, mean1, xb_c, xb_c,
        Wl1, Wl1 + 4096, Wr1, Wr1 + 4096, bl1, bl1 + 64, h1c,
        list, 0b1100, nu, 0, 4, 1);
  k_gemm<<<(N_ENTITY + 63) / 64, 256, 0, stream>>>(mean2, xb_e, nullptr, nullptr,
        Wl1 + 2 * 4096, Wr1 + 2 * 4096, nullptr, nullptr, bl1 + 128, nullptr, h1e,
        nullptr, 0, nullptr, N_ENTITY, 2, 1);
  k_gemm<<<(N_EVIDENCE + 63) / 64, 256, 0, stream>>>(mean3, xb_v, nullptr, nullptr,
        Wl1 + 3 * 4096, Wr1 + 3 * 4096, nullptr, nullptr, bl1 + 192, nullptr, h1v,
        nullptr, 0, nullptr, N_EVIDENCE, 2, 1);

  // ---- layer 2: claims only, compacted ----
  k_agg<<<(2 * BATCH + 31) / 32, 256, 0, stream>>>(
      h1e, h1v, R, col, mean0, mean1, list, nu, 0, N_CLAIM, 0, 0);
  k_gemm<<<(BATCH + 63) / 64, 256, 0, stream>>>(mean0, mean1, h1c, h1c,
        Wl2, Wl2 + 4096, Wr2, Wr2 + 4096, bl2, bl2 + 64, h2c,
        nullptr, 0, nu, 0, 4, 0);

  // ---- classifier ----
  k_out<<<(BATCH * 64 + 255) / 256, 256, 0, stream>>>(h2c, cbi, rank, Wc, bc, out);
}

// Round 5
// 533.297 us; speedup vs baseline: 2.1061x; 1.0313x over previous
//
#include <hip/hip_runtime.h>
#include <hip/hip_bf16.h>
#include <stdint.h>

#define N_CLAIM    100000
#define N_ENTITY   200000
#define N_EVIDENCE 150000
#define NEDGE      2000000
#define F          64
#define NT         550000      // concat dst: t0 claim [0,100K) t1 claim [100K,200K) t2 ent [200K,400K) t3 evid [400K,550K)
#define BATCH      50000

#define BSH   10
#define NBKT  538
#define CAP   24576
#define B3_BLOCKS 2000
#define B3_BPT    500          // blocks per edge type (uniform type per block)
#define B3_CHUNK  4000         // 500*4000 = 2,000,000 edges per type
#define B3_ITER   16           // 16*256 = 4096 >= 4000 (iter 15 partial)
#define NBITS_W   3136         // ceil(100000/32) words for claim bitmask
#define NEB       (N_ENTITY/64)            // 3125 entity blocks
#define NVB       ((N_EVIDENCE+63)/64)     // 2344 evidence blocks

static __device__ __forceinline__ float b2f(unsigned short u){
  return __uint_as_float(((unsigned int)u) << 16);
}
static __device__ __forceinline__ unsigned short f2b(float f){
  unsigned int x = __float_as_uint(f);
  x += 0x7fffu + ((x >> 16) & 1u);   // RNE
  return (unsigned short)(x >> 16);
}

typedef float f32x2v __attribute__((ext_vector_type(2)));

static __device__ __forceinline__ f32x2v pk_add(f32x2v a, f32x2v b){
  f32x2v d;
  asm("v_pk_add_f32 %0, %1, %2" : "=v"(d) : "v"(a), "v"(b));
  return d;
}
// unpack one dword (2 bf16) -> f32x2 {even feat, odd feat}
static __device__ __forceinline__ f32x2v unp(unsigned int w){
  f32x2v r;
  r.x = __uint_as_float(w << 16);
  r.y = __uint_as_float(w & 0xffff0000u);
  return r;
}

// ---------------- fp32 -> bf16 cast: all three feature arrays in one launch ----------------
#define NC4 (N_CLAIM * F / 4)
#define NE4 (N_ENTITY * F / 4)
#define NV4 (N_EVIDENCE * F / 4)
__global__ void k_cast3(const float* __restrict__ a, const float* __restrict__ b,
                        const float* __restrict__ c,
                        unsigned short* __restrict__ oa, unsigned short* __restrict__ ob,
                        unsigned short* __restrict__ oc){
  int i = blockIdx.x * blockDim.x + threadIdx.x;
  const float* in; unsigned short* out; int j;
  if (i < NC4){ in = a; out = oa; j = i; }
  else if (i < NC4 + NE4){ in = b; out = ob; j = i - NC4; }
  else if (i < NC4 + NE4 + NV4){ in = c; out = oc; j = i - NC4 - NE4; }
  else return;
  float4 v = ((const float4*)in)[j];
  ushort4 o;
  o.x = f2b(v.x); o.y = f2b(v.y); o.z = f2b(v.z); o.w = f2b(v.w);
  ((ushort4*)out)[j] = o;
}

// ---------------- used-claim bitmask + compaction ----------------
__global__ void k_mark(const int* __restrict__ cbi, unsigned int* __restrict__ bits){
  int i = blockIdx.x * blockDim.x + threadIdx.x;
  if (i < BATCH){
    int c = cbi[i];
    atomicOr(&bits[c >> 5], 1u << (c & 31));
  }
}
__global__ void k_rank(const unsigned int* __restrict__ bits, int* __restrict__ rank,
                       int* __restrict__ list, int* __restrict__ nu){
  int i = blockIdx.x * blockDim.x + threadIdx.x;
  if (i < N_CLAIM && ((bits[i >> 5] >> (i & 31)) & 1u)){
    int r = atomicAdd(nu, 1);
    rank[i] = r;
    list[r] = i;
  }
}

// ---------------- CSR build: partitioned counting sort ----------------
__global__ void k_init(int* __restrict__ cursor){
  int i = blockIdx.x * blockDim.x + threadIdx.x;
  if (i < NBKT) cursor[i] = i * CAP;
}

// Phase-separated, register-resident bucket scatter.
__global__ __launch_bounds__(256) void k_bscatter(const int* __restrict__ ei,
                                                  const unsigned int* __restrict__ bits,
                                                  int* __restrict__ cursor,
                                                  unsigned int* __restrict__ pairs){
  __shared__ int hcnt[NBKT];
  __shared__ int hpos[NBKT];
  const int toff[4] = {0, N_CLAIM, 2*N_CLAIM, 2*N_CLAIM + N_ENTITY};
  int tid = threadIdx.x;
  int bpt = blockIdx.x / B3_BPT;                     // edge type, uniform per block
  int e0  = (blockIdx.x - bpt * B3_BPT) * B3_CHUNK;  // base edge within type
  int off_t = toff[bpt];
  bool isclaim = (bpt < 2);
  const int* dstp = ei + (size_t)bpt * 2 * NEDGE + NEDGE + e0;
  const int* srcp = ei + (size_t)bpt * 2 * NEDGE + e0;
  for (int b = tid; b < NBKT; b += 256) hcnt[b] = 0;
  __syncthreads();
  unsigned int v[B3_ITER];
  #pragma unroll
  for (int i = 0; i < B3_ITER; ++i){
    int li = i * 256 + tid;
    v[i] = 0xFFFFFFFFu;
    if (li < B3_CHUNK){
      int dst = dstp[li];
      if (!isclaim || ((bits[dst >> 5] >> (dst & 31)) & 1u))
        v[i] = (unsigned int)(dst + off_t);
    }
  }
  #pragma unroll
  for (int i = 0; i < B3_ITER; ++i)
    if (v[i] != 0xFFFFFFFFu) atomicAdd(&hcnt[v[i] >> BSH], 1);
  __syncthreads();
  for (int b = tid; b < NBKT; b += 256){
    int c = hcnt[b];
    hpos[b] = c ? atomicAdd(&cursor[b], c) : 0;
  }
  __syncthreads();
  int s[B3_ITER];
  #pragma unroll
  for (int i = 0; i < B3_ITER; ++i){
    int li = i * 256 + tid;
    s[i] = (li < B3_CHUNK) ? srcp[li] : 0;
  }
  #pragma unroll
  for (int i = 0; i < B3_ITER; ++i){
    if (v[i] != 0xFFFFFFFFu){
      int o = atomicAdd(&hpos[v[i] >> BSH], 1);
      pairs[o] = ((v[i] & ((1u << BSH) - 1)) << 18) | (unsigned int)s[i];
    }
  }
}

__global__ void k_bscan(const int* __restrict__ cursor, int* __restrict__ colBase,
                        int* __restrict__ R){
  __shared__ int s[1024];
  int tid = threadIdx.x;
  int c = (tid < NBKT) ? (cursor[tid] - tid * CAP) : 0;
  s[tid] = c;
  __syncthreads();
  for (int off = 1; off < 1024; off <<= 1){
    int t = (tid >= off) ? s[tid - off] : 0;
    __syncthreads();
    s[tid] += t;
    __syncthreads();
  }
  if (tid < NBKT) colBase[tid] = s[tid] - c;
  if (tid == 1023) R[NT] = s[1023];
}

// 1024 threads: 1 node/thread, 16 waves/block
__global__ __launch_bounds__(1024) void k_csr(const unsigned int* __restrict__ pairs,
                                              const int* __restrict__ cursor,
                                              const int* __restrict__ colBase,
                                              int* __restrict__ R, int* __restrict__ col){
  __shared__ int h[1024];
  __shared__ int s[1024];
  int b = blockIdx.x, tid = threadIdx.x;
  int cnt   = cursor[b] - b * CAP;
  int base  = colBase[b];
  int pbase = b * CAP;
  h[tid] = 0;
  __syncthreads();
  for (int i = tid; i < cnt; i += 1024)
    atomicAdd(&h[pairs[pbase + i] >> 18], 1);
  __syncthreads();
  int c = h[tid];
  s[tid] = c;
  __syncthreads();
  for (int off = 1; off < 1024; off <<= 1){
    int t = (tid >= off) ? s[tid - off] : 0;
    __syncthreads();
    s[tid] += t;
    __syncthreads();
  }
  int ex = s[tid] - c;          // exclusive prefix within bucket
  h[tid] = ex;
  int n = (b << BSH) + tid;
  if (n < NT) R[n] = base + ex;
  __syncthreads();
  for (int i = tid; i < cnt; i += 1024){
    unsigned int p = pairs[pbase + i];
    int r = atomicAdd(&h[p >> 18], 1);
    col[base + r] = (int)(p & 0x3FFFFu);
  }
}

// ---- mean aggregation (claims path): 8 dst rows per wave, 8 lanes x 16B per row ----
__global__ __launch_bounds__(256) void k_agg(const unsigned short* __restrict__ X0,
                                             const unsigned short* __restrict__ X1,
                                             const int* __restrict__ R,
                                             const int* __restrict__ col,
                                             unsigned short* __restrict__ M0,
                                             unsigned short* __restrict__ M1,
                                             const int* __restrict__ list,
                                             const int* __restrict__ nu_ptr,
                                             int RbA, int RbB, int nd0_param, int njobs_param){
  int tid  = threadIdx.x;
  int lane = tid & 63;
  int g    = lane >> 3;          // row group 0..7
  int fl   = lane & 7;           // feature slot: features [8fl, 8fl+8)
  int wv   = (int)blockIdx.x * 4 + (tid >> 6);
  int nu     = list ? *nu_ptr : 0;
  int njobs  = list ? 2 * nu : njobs_param;
  int nd0    = list ? nu : nd0_param;
  int j = wv * 8 + g;
  bool active = j < njobs;
  int sub_t = 0, idx = 0, row = 0, node = 0;
  if (active){
    sub_t = (j >= nd0) ? 1 : 0;
    idx = j - (sub_t ? nd0 : 0);
    row = list ? list[idx] : idx;
    node = (sub_t ? RbB : RbA) + row;
  }
  const unsigned short* X = sub_t ? X1 : X0;
  unsigned short* Mo = sub_t ? M1 : M0;
  int rbeg = 0, rend = 0;
  if (active){ rbeg = R[node]; rend = R[node + 1]; }
  int deg = rend - rbeg;
  f32x2v z = {0.f, 0.f};
  f32x2v acc[4] = {z, z, z, z};
  int cid = 0;
  if (active && fl < deg) cid = col[rbeg + fl];   // first chunk ids
  for (int p = rbeg; p < rend; p += 8){
    int nb = rend - p; if (nb > 8) nb = 8;
    int cc = cid;
    int pn = p + 8;
    int rem = rend - pn;
    if (rem > 0 && fl < rem) cid = col[pn + fl];  // prefetch next chunk ids
    #pragma unroll
    for (int k = 0; k < 8; ++k){
      int c = __shfl(cc, (g << 3) + k, 64);
      if (k < nb){
        uint4 d = *(const uint4*)(X + (long long)c * F + fl * 8);
        acc[0] = pk_add(acc[0], unp(d.x));
        acc[1] = pk_add(acc[1], unp(d.y));
        acc[2] = pk_add(acc[2], unp(d.z));
        acc[3] = pk_add(acc[3], unp(d.w));
      }
    }
  }
  if (active){
    float r = deg ? (1.0f / (float)deg) : 0.f;
    uint4 o;
    o.x = ((unsigned int)f2b(acc[0].y * r) << 16) | f2b(acc[0].x * r);
    o.y = ((unsigned int)f2b(acc[1].y * r) << 16) | f2b(acc[1].x * r);
    o.z = ((unsigned int)f2b(acc[2].y * r) << 16) | f2b(acc[2].x * r);
    o.w = ((unsigned int)f2b(acc[3].y * r) << 16) | f2b(acc[3].x * r);
    *(uint4*)(Mo + (long long)idx * F + fl * 8) = o;
  }
}

typedef __bf16 bf16x8 __attribute__((ext_vector_type(8)));
typedef float  f32x4  __attribute__((ext_vector_type(4)));
#define WT_STRIDE 72

// ---- fused mean-aggregate + 2-source GEMM for entity & evidence layer 1 ----
// 512 threads, 64 rows/block. Phase 1: 8 waves x 8 rows gather-mean (from claim
// features) -> bf16 tile in LDS (stride 72, conflict-free). Phase 2: 8 waves x
// 2 (16x16) output tiles: MFMA(mean_lds x Wl + root_glb x Wr), bias+relu, store.
__global__ __launch_bounds__(512) void k_aggemm(
    const unsigned short* __restrict__ Xg,   // gather table: claim bf16 features
    const unsigned short* __restrict__ Xe,   // entity root features
    const unsigned short* __restrict__ Xv,   // evidence root features
    const int* __restrict__ R, const int* __restrict__ col,
    const float* __restrict__ Wl, const float* __restrict__ Wr,
    const float* __restrict__ bl,
    unsigned short* __restrict__ He, unsigned short* __restrict__ Hv)
{
  __shared__ __align__(16) unsigned short WTm[64 * WT_STRIDE];  // lin_l (mean path)
  __shared__ __align__(16) unsigned short WTr[64 * WT_STRIDE];  // lin_r (root path)
  __shared__ __align__(16) unsigned short MT [64 * WT_STRIDE];  // mean tile
  int b = blockIdx.x;
  int seg, m0, Rb, Ms;
  const unsigned short* Xroot;
  unsigned short* Hout;
  if (b < NEB){ seg = 0; m0 = b * 64;         Rb = 2*N_CLAIM;            Ms = N_ENTITY;   Xroot = Xe; Hout = He; }
  else        { seg = 1; m0 = (b - NEB) * 64; Rb = 2*N_CLAIM + N_ENTITY; Ms = N_EVIDENCE; Xroot = Xv; Hout = Hv; }
  int tid = threadIdx.x;
  const float* Wlp = Wl + (size_t)(2 + seg) * 4096;
  const float* Wrp = Wr + (size_t)(2 + seg) * 4096;
  #pragma unroll
  for (int q = 0; q < 8; q++){
    int idx = q * 512 + tid;
    int k = idx >> 6, n = idx & 63;
    WTm[n * WT_STRIDE + k] = f2b(Wlp[idx]);
    WTr[n * WT_STRIDE + k] = f2b(Wrp[idx]);
  }
  // ---- phase 1: means ----
  int lane = tid & 63;
  int wv   = tid >> 6;          // 0..7
  int g    = lane >> 3;         // 0..7
  int fl   = lane & 7;
  int rowl = wv * 8 + g;        // 0..63
  int rowg = m0 + rowl;
  bool act = rowg < Ms;
  int rbeg = 0, rend = 0;
  if (act){ rbeg = R[Rb + rowg]; rend = R[Rb + rowg + 1]; }
  int deg = rend - rbeg;
  f32x2v z = {0.f, 0.f};
  f32x2v acc[4] = {z, z, z, z};
  int cid = 0;
  if (fl < deg) cid = col[rbeg + fl];
  for (int p = rbeg; p < rend; p += 8){
    int nb = rend - p; if (nb > 8) nb = 8;
    int cc = cid;
    int rem = rend - (p + 8);
    if (rem > 0 && fl < rem) cid = col[p + 8 + fl];
    #pragma unroll
    for (int k = 0; k < 8; ++k){
      int c = __shfl(cc, (g << 3) + k, 64);
      if (k < nb){
        uint4 d = *(const uint4*)(Xg + (long long)c * F + fl * 8);
        acc[0] = pk_add(acc[0], unp(d.x));
        acc[1] = pk_add(acc[1], unp(d.y));
        acc[2] = pk_add(acc[2], unp(d.z));
        acc[3] = pk_add(acc[3], unp(d.w));
      }
    }
  }
  {
    float r = deg ? (1.0f / (float)deg) : 0.f;
    uint4 o;
    o.x = ((unsigned int)f2b(acc[0].y * r) << 16) | f2b(acc[0].x * r);
    o.y = ((unsigned int)f2b(acc[1].y * r) << 16) | f2b(acc[1].x * r);
    o.z = ((unsigned int)f2b(acc[2].y * r) << 16) | f2b(acc[2].x * r);
    o.w = ((unsigned int)f2b(acc[3].y * r) << 16) | f2b(acc[3].x * r);
    *(uint4*)(MT + rowl * WT_STRIDE + fl * 8) = o;    // zeros when inactive
  }
  __syncthreads();
  // ---- phase 2: GEMM. wave -> row-tile rt = wv>>1, col-tiles {c0, c0+1} ----
  int rt = wv >> 1;
  int c0 = (wv & 1) * 2;
  int quad = lane >> 4, l16 = lane & 15;
  int arow = m0 + rt * 16 + l16; if (arow >= Ms) arow = Ms - 1;
  f32x4 zz = {0.f, 0.f, 0.f, 0.f};
  f32x4 gacc[2] = {zz, zz};
  #pragma unroll
  for (int kk = 0; kk < 64; kk += 32){
    bf16x8 am = *(const bf16x8*)(MT + (rt * 16 + l16) * WT_STRIDE + kk + quad * 8);
    bf16x8 ar = *(const bf16x8*)(Xroot + (long long)arow * F + kk + quad * 8);
    #pragma unroll
    for (int c = 0; c < 2; c++){
      bf16x8 bm = *(const bf16x8*)(WTm + ((c0 + c) * 16 + l16) * WT_STRIDE + kk + quad * 8);
      bf16x8 br = *(const bf16x8*)(WTr + ((c0 + c) * 16 + l16) * WT_STRIDE + kk + quad * 8);
      gacc[c] = __builtin_amdgcn_mfma_f32_16x16x32_bf16(am, bm, gacc[c], 0, 0, 0);
      gacc[c] = __builtin_amdgcn_mfma_f32_16x16x32_bf16(ar, br, gacc[c], 0, 0, 0);
    }
  }
  const float* blp = bl + (size_t)(2 + seg) * 64;
  #pragma unroll
  for (int c = 0; c < 2; c++){
    int n = (c0 + c) * 16 + l16;
    float bv = blp[n];
    #pragma unroll
    for (int r4 = 0; r4 < 4; r4++){
      int row = m0 + rt * 16 + quad * 4 + r4;
      if (row < Ms){
        float v2 = gacc[c][r4] + bv;
        Hout[(long long)row * F + n] = f2b(fmaxf(v2, 0.f));
      }
    }
  }
}

// ---- fused multi-source GEMM (claims path): H = act(sum_j Aj@Wj + bias) ----
__global__ __launch_bounds__(256) void k_gemm(
    const unsigned short* __restrict__ A0, const unsigned short* __restrict__ A1,
    const unsigned short* __restrict__ A2, const unsigned short* __restrict__ A3,
    const float* __restrict__ W0, const float* __restrict__ W1,
    const float* __restrict__ W2, const float* __restrict__ W3,
    const float* __restrict__ b0, const float* __restrict__ b1,
    unsigned short* __restrict__ Hout,
    const int* __restrict__ Alist, int amask,
    const int* __restrict__ Mptr, int Mparam, int ns, int relu)
{
  int M = Mptr ? *Mptr : Mparam;
  if ((int)blockIdx.x * 64 >= M) return;     // block-uniform early exit
  __shared__ __align__(16) unsigned short WT[4 * 64 * WT_STRIDE];
  const float* Ws[4] = {W0, W1, W2, W3};
  const unsigned short* As[4] = {A0, A1, A2, A3};
  int tid = threadIdx.x;
  for (int j = 0; j < ns; j++){
    const float* Wj = Ws[j];
    #pragma unroll
    for (int q = 0; q < 16; q++){
      int idx = q * 256 + tid;
      int k = idx >> 6, n = idx & 63;
      WT[j * 64 * WT_STRIDE + n * WT_STRIDE + k] = f2b(Wj[idx]);
    }
  }
  __syncthreads();
  int wave = tid >> 6, lane = tid & 63;
  int quad = lane >> 4, l16 = lane & 15;
  int m0 = blockIdx.x * 64 + wave * 16;
  int arow = m0 + l16; if (arow >= M) arow = M - 1;
  int arows[4];
  #pragma unroll
  for (int j = 0; j < 4; j++)
    arows[j] = ((amask >> j) & 1) ? Alist[arow] : arow;
  f32x4 z = {0.f, 0.f, 0.f, 0.f};
  f32x4 acc[4] = {z, z, z, z};
  for (int j = 0; j < ns; j++){
    const unsigned short* Aj = As[j];
    #pragma unroll
    for (int kk = 0; kk < 64; kk += 32){
      bf16x8 af = *(const bf16x8*)(Aj + (long long)arows[j] * F + kk + quad * 8);
      #pragma unroll
      for (int c = 0; c < 4; c++){
        const unsigned short* bp = &WT[j * 64 * WT_STRIDE + (c * 16 + l16) * WT_STRIDE + kk + quad * 8];
        bf16x8 bfr = *(const bf16x8*)bp;
        acc[c] = __builtin_amdgcn_mfma_f32_16x16x32_bf16(af, bfr, acc[c], 0, 0, 0);
      }
    }
  }
  #pragma unroll
  for (int c = 0; c < 4; c++){
    int n = c * 16 + l16;
    float bv = b0[n] + (b1 ? b1[n] : 0.f);
    #pragma unroll
    for (int r = 0; r < 4; r++){
      int row = m0 + quad * 4 + r;
      if (row < M){
        float v = acc[c][r] + bv;
        if (relu) v = fmaxf(v, 0.f);
        Hout[(long long)row * F + n] = f2b(v);
      }
    }
  }
}

// ---------------- final classifier: wave per batch row; fp32 out ----------------
__global__ void k_out(const unsigned short* __restrict__ h2,
                      const int* __restrict__ cbi,
                      const int* __restrict__ rank,
                      const float* __restrict__ Wc,
                      const float* __restrict__ bcp,
                      float* __restrict__ out){
  int w = (int)(((unsigned)blockIdx.x * blockDim.x + threadIdx.x) >> 6);
  int lane = threadIdx.x & 63;
  if (w >= BATCH) return;
  int rk = rank[cbi[w]];
  float v = b2f(h2[(long long)rk * F + lane]);
  float p0 = v * Wc[lane * 2];
  float p1 = v * Wc[lane * 2 + 1];
  for (int off = 32; off; off >>= 1){
    p0 += __shfl_xor(p0, off, 64);
    p1 += __shfl_xor(p1, off, 64);
  }
  if (lane == 0){
    out[2 * w]     = p0 + bcp[0];
    out[2 * w + 1] = p1 + bcp[1];
  }
}

extern "C" void kernel_launch(void* const* d_in, const int* in_sizes, int n_in,
                              void* d_out, int out_size, void* d_ws, size_t ws_size,
                              hipStream_t stream)
{
  const float* x_c = (const float*)d_in[0];
  const float* x_e = (const float*)d_in[1];
  const float* x_v = (const float*)d_in[2];
  const int*   ei  = (const int*)d_in[3];
  const int*   cbi = (const int*)d_in[4];
  const float* Wl1 = (const float*)d_in[5];
  const float* bl1 = (const float*)d_in[6];
  const float* Wr1 = (const float*)d_in[7];
  const float* Wl2 = (const float*)d_in[8];
  const float* bl2 = (const float*)d_in[9];
  const float* Wr2 = (const float*)d_in[10];
  const float* Wc  = (const float*)d_in[11];
  const float* bc  = (const float*)d_in[12];
  float* out = (float*)d_out;

  char* ws = (char*)d_ws;
  size_t off = 0;
  auto alloc = [&](size_t bytes) -> char* {
    char* p = ws + off;
    off += (bytes + 255) & ~(size_t)255;
    return p;
  };
  int* R       = (int*)alloc((size_t)(NT + 1) * 4);
  int* cursor  = (int*)alloc((size_t)NBKT * 4);
  int* colBase = (int*)alloc((size_t)NBKT * 4);
  unsigned int* bits = (unsigned int*)alloc((size_t)NBITS_W * 4);
  int* rank    = (int*)alloc((size_t)N_CLAIM * 4);
  int* list    = (int*)alloc((size_t)BATCH * 4);
  int* nu      = (int*)alloc(256);
  int* col     = (int*)alloc((size_t)4 * NEDGE * 4);
  unsigned int* pairs = (unsigned int*)alloc((size_t)NBKT * CAP * 4);   // dead after k_csr
  unsigned short* xb_c  = (unsigned short*)alloc((size_t)N_CLAIM    * F * 2);
  unsigned short* xb_e  = (unsigned short*)alloc((size_t)N_ENTITY   * F * 2);
  unsigned short* xb_v  = (unsigned short*)alloc((size_t)N_EVIDENCE * F * 2);
  unsigned short* mean0 = (unsigned short*)alloc((size_t)BATCH * F * 2);   // compacted
  unsigned short* mean1 = (unsigned short*)alloc((size_t)BATCH * F * 2);   // compacted
  unsigned short* h1c   = (unsigned short*)alloc((size_t)BATCH * F * 2);   // compacted
  unsigned short* h1e   = (unsigned short*)alloc((size_t)N_ENTITY   * F * 2);
  unsigned short* h1v   = (unsigned short*)alloc((size_t)N_EVIDENCE * F * 2);
  unsigned short* h2c   = (unsigned short*)pairs;   // compacted; alias dead pairs region

  hipMemsetAsync(bits, 0, (size_t)NBITS_W * 4, stream);
  hipMemsetAsync(nu, 0, 4, stream);

  k_mark<<<(BATCH + 255) / 256, 256, 0, stream>>>(cbi, bits);
  k_rank<<<(N_CLAIM + 255) / 256, 256, 0, stream>>>(bits, rank, list, nu);
  k_cast3<<<(NC4 + NE4 + NV4 + 255) / 256, 256, 0, stream>>>(x_c, x_e, x_v, xb_c, xb_e, xb_v);

  k_init<<<(NBKT + 255) / 256, 256, 0, stream>>>(cursor);
  k_bscatter<<<B3_BLOCKS, 256, 0, stream>>>(ei, bits, cursor, pairs);
  k_bscan<<<1, 1024, 0, stream>>>(cursor, colBase, R);
  k_csr<<<NBKT, 1024, 0, stream>>>(pairs, cursor, colBase, R, col);

  // ---- layer 1: claims aggregation + transform (compacted) ----
  k_agg<<<(2 * BATCH + 31) / 32, 256, 0, stream>>>(
      xb_e, xb_v, R, col, mean0, mean1, list, nu, 0, N_CLAIM, 0, 0);
  k_gemm<<<(BATCH + 63) / 64, 256, 0, stream>>>(mean0, mean1, xb_c, xb_c,
        Wl1, Wl1 + 4096, Wr1, Wr1 + 4096, bl1, bl1 + 64, h1c,
        list, 0b1100, nu, 0, 4, 1);

  // ---- layer 1: entity + evidence fused agg+GEMM ----
  k_aggemm<<<NEB + NVB, 512, 0, stream>>>(
      xb_c, xb_e, xb_v, R, col, Wl1, Wr1, bl1, h1e, h1v);

  // ---- layer 2: claims only, compacted ----
  k_agg<<<(2 * BATCH + 31) / 32, 256, 0, stream>>>(
      h1e, h1v, R, col, mean0, mean1, list, nu, 0, N_CLAIM, 0, 0);
  k_gemm<<<(BATCH + 63) / 64, 256, 0, stream>>>(mean0, mean1, h1c, h1c,
        Wl2, Wl2 + 4096, Wr2, Wr2 + 4096, bl2, bl2 + 64, h2c,
        nullptr, 0, nu, 0, 4, 0);

  // ---- classifier ----
  k_out<<<(BATCH * 64 + 255) / 256, 256, 0, stream>>>(h2c, cbi, rank, Wc, bc, out);
}

// Round 6
// 513.911 us; speedup vs baseline: 2.1856x; 1.0377x over previous
//
#include <hip/hip_runtime.h>
#include <hip/hip_bf16.h>
#include <stdint.h>

#define N_CLAIM    100000
#define N_ENTITY   200000
#define N_EVIDENCE 150000
#define NEDGE      2000000
#define F          64
#define NT         550000      // concat dst: t0 claim [0,100K) t1 claim [100K,200K) t2 ent [200K,400K) t3 evid [400K,550K)
#define BATCH      50000

#define BSH   10
#define NBKT  538
#define CAP   24576
#define B3_BLOCKS 2000
#define B3_BPT    500          // blocks per edge type (uniform type per block)
#define B3_CHUNK  4000         // 500*4000 = 2,000,000 edges per type
#define B3_ITER   16           // 16*256 = 4096 >= 4000 (iter 15 partial)
#define NBITS_W   3136         // ceil(100000/32) words for claim bitmask
#define NEB       (N_ENTITY/64)            // 3125 entity blocks
#define NVB       ((N_EVIDENCE+63)/64)     // 2344 evidence blocks

// LDS tile: 64 rows x 64 shorts, stored as 8 x 16B chunks per row with XOR swizzle
// (chunk ^ row&7). Conflict-free b128 reads (8 distinct 4-bank starts / 8 lanes each,
// uniform) and uniform vector writes. Index in shorts:
#define SWZ(row, chunk) (((row) << 6) + ((((chunk) ^ ((row) & 7))) << 3))

static __device__ __forceinline__ float b2f(unsigned short u){
  return __uint_as_float(((unsigned int)u) << 16);
}
static __device__ __forceinline__ unsigned short f2b(float f){
  unsigned int x = __float_as_uint(f);
  x += 0x7fffu + ((x >> 16) & 1u);   // RNE
  return (unsigned short)(x >> 16);
}

typedef float f32x2v __attribute__((ext_vector_type(2)));

static __device__ __forceinline__ f32x2v pk_add(f32x2v a, f32x2v b){
  f32x2v d;
  asm("v_pk_add_f32 %0, %1, %2" : "=v"(d) : "v"(a), "v"(b));
  return d;
}
// unpack one dword (2 bf16) -> f32x2 {even feat, odd feat}
static __device__ __forceinline__ f32x2v unp(unsigned int w){
  f32x2v r;
  r.x = __uint_as_float(w << 16);
  r.y = __uint_as_float(w & 0xffff0000u);
  return r;
}

// ---------------- fp32 -> bf16 cast: all three feature arrays in one launch ----------------
#define NC4 (N_CLAIM * F / 4)
#define NE4 (N_ENTITY * F / 4)
#define NV4 (N_EVIDENCE * F / 4)
__global__ void k_cast3(const float* __restrict__ a, const float* __restrict__ b,
                        const float* __restrict__ c,
                        unsigned short* __restrict__ oa, unsigned short* __restrict__ ob,
                        unsigned short* __restrict__ oc){
  int i = blockIdx.x * blockDim.x + threadIdx.x;
  const float* in; unsigned short* out; int j;
  if (i < NC4){ in = a; out = oa; j = i; }
  else if (i < NC4 + NE4){ in = b; out = ob; j = i - NC4; }
  else if (i < NC4 + NE4 + NV4){ in = c; out = oc; j = i - NC4 - NE4; }
  else return;
  float4 v = ((const float4*)in)[j];
  ushort4 o;
  o.x = f2b(v.x); o.y = f2b(v.y); o.z = f2b(v.z); o.w = f2b(v.w);
  ((ushort4*)out)[j] = o;
}

// ---------------- used-claim bitmask + compaction ----------------
__global__ void k_mark(const int* __restrict__ cbi, unsigned int* __restrict__ bits){
  int i = blockIdx.x * blockDim.x + threadIdx.x;
  if (i < BATCH){
    int c = cbi[i];
    atomicOr(&bits[c >> 5], 1u << (c & 31));
  }
}
__global__ void k_rank(const unsigned int* __restrict__ bits, int* __restrict__ rank,
                       int* __restrict__ list, int* __restrict__ nu){
  int i = blockIdx.x * blockDim.x + threadIdx.x;
  if (i < N_CLAIM && ((bits[i >> 5] >> (i & 31)) & 1u)){
    int r = atomicAdd(nu, 1);
    rank[i] = r;
    list[r] = i;
  }
}

// ---------------- CSR build: partitioned counting sort ----------------
__global__ void k_init(int* __restrict__ cursor){
  int i = blockIdx.x * blockDim.x + threadIdx.x;
  if (i < NBKT) cursor[i] = i * CAP;
}

// Phase-separated, register-resident bucket scatter.
__global__ __launch_bounds__(256) void k_bscatter(const int* __restrict__ ei,
                                                  const unsigned int* __restrict__ bits,
                                                  int* __restrict__ cursor,
                                                  unsigned int* __restrict__ pairs){
  __shared__ int hcnt[NBKT];
  __shared__ int hpos[NBKT];
  const int toff[4] = {0, N_CLAIM, 2*N_CLAIM, 2*N_CLAIM + N_ENTITY};
  int tid = threadIdx.x;
  int bpt = blockIdx.x / B3_BPT;                     // edge type, uniform per block
  int e0  = (blockIdx.x - bpt * B3_BPT) * B3_CHUNK;  // base edge within type
  int off_t = toff[bpt];
  bool isclaim = (bpt < 2);
  const int* dstp = ei + (size_t)bpt * 2 * NEDGE + NEDGE + e0;
  const int* srcp = ei + (size_t)bpt * 2 * NEDGE + e0;
  for (int b = tid; b < NBKT; b += 256) hcnt[b] = 0;
  __syncthreads();
  unsigned int v[B3_ITER];
  #pragma unroll
  for (int i = 0; i < B3_ITER; ++i){
    int li = i * 256 + tid;
    v[i] = 0xFFFFFFFFu;
    if (li < B3_CHUNK){
      int dst = dstp[li];
      if (!isclaim || ((bits[dst >> 5] >> (dst & 31)) & 1u))
        v[i] = (unsigned int)(dst + off_t);
    }
  }
  #pragma unroll
  for (int i = 0; i < B3_ITER; ++i)
    if (v[i] != 0xFFFFFFFFu) atomicAdd(&hcnt[v[i] >> BSH], 1);
  __syncthreads();
  for (int b = tid; b < NBKT; b += 256){
    int c = hcnt[b];
    hpos[b] = c ? atomicAdd(&cursor[b], c) : 0;
  }
  __syncthreads();
  int s[B3_ITER];
  #pragma unroll
  for (int i = 0; i < B3_ITER; ++i){
    int li = i * 256 + tid;
    s[i] = (li < B3_CHUNK) ? srcp[li] : 0;
  }
  #pragma unroll
  for (int i = 0; i < B3_ITER; ++i){
    if (v[i] != 0xFFFFFFFFu){
      int o = atomicAdd(&hpos[v[i] >> BSH], 1);
      pairs[o] = ((v[i] & ((1u << BSH) - 1)) << 18) | (unsigned int)s[i];
    }
  }
}

__global__ void k_bscan(const int* __restrict__ cursor, int* __restrict__ colBase,
                        int* __restrict__ R){
  __shared__ int s[1024];
  int tid = threadIdx.x;
  int c = (tid < NBKT) ? (cursor[tid] - tid * CAP) : 0;
  s[tid] = c;
  __syncthreads();
  for (int off = 1; off < 1024; off <<= 1){
    int t = (tid >= off) ? s[tid - off] : 0;
    __syncthreads();
    s[tid] += t;
    __syncthreads();
  }
  if (tid < NBKT) colBase[tid] = s[tid] - c;
  if (tid == 1023) R[NT] = s[1023];
}

// 1024 threads: 1 node/thread, 16 waves/block
__global__ __launch_bounds__(1024) void k_csr(const unsigned int* __restrict__ pairs,
                                              const int* __restrict__ cursor,
                                              const int* __restrict__ colBase,
                                              int* __restrict__ R, int* __restrict__ col){
  __shared__ int h[1024];
  __shared__ int s[1024];
  int b = blockIdx.x, tid = threadIdx.x;
  int cnt   = cursor[b] - b * CAP;
  int base  = colBase[b];
  int pbase = b * CAP;
  h[tid] = 0;
  __syncthreads();
  for (int i = tid; i < cnt; i += 1024)
    atomicAdd(&h[pairs[pbase + i] >> 18], 1);
  __syncthreads();
  int c = h[tid];
  s[tid] = c;
  __syncthreads();
  for (int off = 1; off < 1024; off <<= 1){
    int t = (tid >= off) ? s[tid - off] : 0;
    __syncthreads();
    s[tid] += t;
    __syncthreads();
  }
  int ex = s[tid] - c;          // exclusive prefix within bucket
  h[tid] = ex;
  int n = (b << BSH) + tid;
  if (n < NT) R[n] = base + ex;
  __syncthreads();
  for (int i = tid; i < cnt; i += 1024){
    unsigned int p = pairs[pbase + i];
    int r = atomicAdd(&h[p >> 18], 1);
    col[base + r] = (int)(p & 0x3FFFFu);
  }
}

typedef __bf16 bf16x8 __attribute__((ext_vector_type(8)));
typedef float  f32x4  __attribute__((ext_vector_type(4)));

// stage one 64x64 fp32 weight matrix -> swizzled bf16 LDS tile; 512 threads,
// coalesced global reads (consecutive lanes read consecutive n for fixed k),
// uniform 16B chunk writes. oct = tid>>6, n = tid&63.
static __device__ __forceinline__ void stage_w(const float* __restrict__ W,
                                               unsigned short* __restrict__ T,
                                               int n, int oct){
  unsigned int pk[4];
  #pragma unroll
  for (int i = 0; i < 4; i++){
    float lo = W[(oct * 8 + 2 * i)     * 64 + n];
    float hi = W[(oct * 8 + 2 * i + 1) * 64 + n];
    pk[i] = ((unsigned int)f2b(hi) << 16) | f2b(lo);
  }
  *(uint4*)(T + SWZ(n, oct)) = *(uint4*)pk;
}

// gather-mean of one row group (8 lanes/row, 16B/lane) -> accumulators
static __device__ __forceinline__ void gather_mean(
    const unsigned short* __restrict__ X, const int* __restrict__ col,
    int rbeg, int rend, int g, int fl, f32x2v acc[4]){
  int cid = 0;
  int deg = rend - rbeg;
  if (fl < deg) cid = col[rbeg + fl];
  for (int p = rbeg; p < rend; p += 8){
    int nb = rend - p; if (nb > 8) nb = 8;
    int cc = cid;
    int rem = rend - (p + 8);
    if (rem > 0 && fl < rem) cid = col[p + 8 + fl];
    #pragma unroll
    for (int k = 0; k < 8; ++k){
      int c = __shfl(cc, (g << 3) + k, 64);
      if (k < nb){
        uint4 d = *(const uint4*)(X + (long long)c * F + fl * 8);
        acc[0] = pk_add(acc[0], unp(d.x));
        acc[1] = pk_add(acc[1], unp(d.y));
        acc[2] = pk_add(acc[2], unp(d.z));
        acc[3] = pk_add(acc[3], unp(d.w));
      }
    }
  }
}

static __device__ __forceinline__ uint4 mean_pack(f32x2v acc[4], int deg){
  float r = deg ? (1.0f / (float)deg) : 0.f;
  uint4 o;
  o.x = ((unsigned int)f2b(acc[0].y * r) << 16) | f2b(acc[0].x * r);
  o.y = ((unsigned int)f2b(acc[1].y * r) << 16) | f2b(acc[1].x * r);
  o.z = ((unsigned int)f2b(acc[2].y * r) << 16) | f2b(acc[2].x * r);
  o.w = ((unsigned int)f2b(acc[3].y * r) << 16) | f2b(acc[3].x * r);
  return o;
}

// ---- fused mean-aggregate + 2-source GEMM for entity & evidence layer 1 ----
__global__ __launch_bounds__(512) void k_aggemm(
    const unsigned short* __restrict__ Xg,   // gather table: claim bf16 features
    const unsigned short* __restrict__ Xe,   // entity root features
    const unsigned short* __restrict__ Xv,   // evidence root features
    const int* __restrict__ R, const int* __restrict__ col,
    const float* __restrict__ Wl, const float* __restrict__ Wr,
    const float* __restrict__ bl,
    unsigned short* __restrict__ He, unsigned short* __restrict__ Hv)
{
  __shared__ __align__(16) unsigned short WTm[4096];  // lin_l (mean path), swizzled
  __shared__ __align__(16) unsigned short WTr[4096];  // lin_r (root path), swizzled
  __shared__ __align__(16) unsigned short MT [4096];  // mean tile, swizzled
  int b = blockIdx.x;
  int seg, m0, Rb, Ms;
  const unsigned short* Xroot;
  unsigned short* Hout;
  if (b < NEB){ seg = 0; m0 = b * 64;         Rb = 2*N_CLAIM;            Ms = N_ENTITY;   Xroot = Xe; Hout = He; }
  else        { seg = 1; m0 = (b - NEB) * 64; Rb = 2*N_CLAIM + N_ENTITY; Ms = N_EVIDENCE; Xroot = Xv; Hout = Hv; }
  int tid = threadIdx.x;
  int sn = tid & 63, soct = tid >> 6;
  stage_w(Wl + (size_t)(2 + seg) * 4096, WTm, sn, soct);
  stage_w(Wr + (size_t)(2 + seg) * 4096, WTr, sn, soct);
  // ---- phase 1: means ----
  int lane = tid & 63;
  int wv   = tid >> 6;          // 0..7
  int g    = lane >> 3;         // 0..7
  int fl   = lane & 7;
  int rowl = wv * 8 + g;        // 0..63
  int rowg = m0 + rowl;
  bool act = rowg < Ms;
  int rbeg = 0, rend = 0;
  if (act){ rbeg = R[Rb + rowg]; rend = R[Rb + rowg + 1]; }
  f32x2v z = {0.f, 0.f};
  f32x2v acc[4] = {z, z, z, z};
  gather_mean(Xg, col, rbeg, rend, g, fl, acc);
  *(uint4*)(MT + SWZ(rowl, fl)) = mean_pack(acc, rend - rbeg);
  __syncthreads();
  // ---- phase 2: GEMM. wave -> row-tile rt = wv>>1, col-tiles {c0, c0+1} ----
  int rt = wv >> 1;
  int c0 = (wv & 1) * 2;
  int quad = lane >> 4, l16 = lane & 15;
  int arow = m0 + rt * 16 + l16; if (arow >= Ms) arow = Ms - 1;
  f32x4 zz = {0.f, 0.f, 0.f, 0.f};
  f32x4 gacc[2] = {zz, zz};
  #pragma unroll
  for (int kk = 0; kk < 64; kk += 32){
    int ch = (kk >> 3) + quad;
    bf16x8 am = *(const bf16x8*)(MT + SWZ(rt * 16 + l16, ch));
    bf16x8 ar = *(const bf16x8*)(Xroot + (long long)arow * F + kk + quad * 8);
    #pragma unroll
    for (int c = 0; c < 2; c++){
      int bn = (c0 + c) * 16 + l16;
      bf16x8 bm = *(const bf16x8*)(WTm + SWZ(bn, ch));
      bf16x8 br = *(const bf16x8*)(WTr + SWZ(bn, ch));
      gacc[c] = __builtin_amdgcn_mfma_f32_16x16x32_bf16(am, bm, gacc[c], 0, 0, 0);
      gacc[c] = __builtin_amdgcn_mfma_f32_16x16x32_bf16(ar, br, gacc[c], 0, 0, 0);
    }
  }
  const float* blp = bl + (size_t)(2 + seg) * 64;
  #pragma unroll
  for (int c = 0; c < 2; c++){
    int n = (c0 + c) * 16 + l16;
    float bv = blp[n];
    #pragma unroll
    for (int r4 = 0; r4 < 4; r4++){
      int row = m0 + rt * 16 + quad * 4 + r4;
      if (row < Ms){
        float v2 = gacc[c][r4] + bv;
        Hout[(long long)row * F + n] = f2b(fmaxf(v2, 0.f));
      }
    }
  }
}

// ---- fused claims layer: gather ent+evid means -> LDS, 4-source MFMA GEMM ----
// sources: mean0@W0 + mean1@W1 + root@W2 + root@W3 + (b0+b1), optional relu.
// Gather nodes: list[row] (+0 / +N_CLAIM). Root: list[row] if rootlist else row.
__global__ __launch_bounds__(512) void k_cagg(
    const unsigned short* __restrict__ Xg0,  // gather table seg0 (ent feats)
    const unsigned short* __restrict__ Xg1,  // gather table seg1 (evid feats)
    const unsigned short* __restrict__ Xr,   // root features
    const int* __restrict__ R, const int* __restrict__ col,
    const int* __restrict__ list, const int* __restrict__ nu_ptr,
    const float* __restrict__ W0, const float* __restrict__ W1,
    const float* __restrict__ W2, const float* __restrict__ W3,
    const float* __restrict__ b0, const float* __restrict__ b1,
    unsigned short* __restrict__ Hout, int rootlist, int relu)
{
  int M = *nu_ptr;
  if ((int)blockIdx.x * 64 >= M) return;     // block-uniform early exit
  __shared__ __align__(16) unsigned short WT[4 * 4096];  // 4 weight tiles, swizzled
  __shared__ __align__(16) unsigned short MT[2 * 4096];  // 2 mean tiles, swizzled
  int tid = threadIdx.x;
  int sn = tid & 63, soct = tid >> 6;
  stage_w(W0, WT,            sn, soct);
  stage_w(W1, WT + 4096,     sn, soct);
  stage_w(W2, WT + 2 * 4096, sn, soct);
  stage_w(W3, WT + 3 * 4096, sn, soct);
  int m0 = blockIdx.x * 64;
  int lane = tid & 63;
  int wv   = tid >> 6;
  int g    = lane >> 3;
  int fl   = lane & 7;
  int rowl = wv * 8 + g;
  int rowg = m0 + rowl;
  bool act = rowg < M;
  int node0 = act ? list[rowg] : 0;
  #pragma unroll
  for (int seg = 0; seg < 2; ++seg){
    const unsigned short* Xg = seg ? Xg1 : Xg0;
    int node = node0 + (seg ? N_CLAIM : 0);
    int rbeg = 0, rend = 0;
    if (act){ rbeg = R[node]; rend = R[node + 1]; }
    f32x2v z = {0.f, 0.f};
    f32x2v acc[4] = {z, z, z, z};
    gather_mean(Xg, col, rbeg, rend, g, fl, acc);
    *(uint4*)(MT + seg * 4096 + SWZ(rowl, fl)) = mean_pack(acc, rend - rbeg);
  }
  __syncthreads();
  // ---- GEMM phase ----
  int rt = wv >> 1;
  int c0 = (wv & 1) * 2;
  int quad = lane >> 4, l16 = lane & 15;
  int arow = m0 + rt * 16 + l16; if (arow >= M) arow = M - 1;
  long long rrow = rootlist ? list[arow] : arow;
  f32x4 zz = {0.f, 0.f, 0.f, 0.f};
  f32x4 gacc[2] = {zz, zz};
  #pragma unroll
  for (int kk = 0; kk < 64; kk += 32){
    int ch = (kk >> 3) + quad;
    bf16x8 a0 = *(const bf16x8*)(MT + SWZ(rt * 16 + l16, ch));
    bf16x8 a1 = *(const bf16x8*)(MT + 4096 + SWZ(rt * 16 + l16, ch));
    bf16x8 ar = *(const bf16x8*)(Xr + rrow * F + kk + quad * 8);
    #pragma unroll
    for (int c = 0; c < 2; c++){
      int bn = (c0 + c) * 16 + l16;
      bf16x8 w0 = *(const bf16x8*)(WT +            SWZ(bn, ch));
      bf16x8 w1 = *(const bf16x8*)(WT + 4096     + SWZ(bn, ch));
      bf16x8 w2 = *(const bf16x8*)(WT + 2 * 4096 + SWZ(bn, ch));
      bf16x8 w3 = *(const bf16x8*)(WT + 3 * 4096 + SWZ(bn, ch));
      gacc[c] = __builtin_amdgcn_mfma_f32_16x16x32_bf16(a0, w0, gacc[c], 0, 0, 0);
      gacc[c] = __builtin_amdgcn_mfma_f32_16x16x32_bf16(a1, w1, gacc[c], 0, 0, 0);
      gacc[c] = __builtin_amdgcn_mfma_f32_16x16x32_bf16(ar, w2, gacc[c], 0, 0, 0);
      gacc[c] = __builtin_amdgcn_mfma_f32_16x16x32_bf16(ar, w3, gacc[c], 0, 0, 0);
    }
  }
  #pragma unroll
  for (int c = 0; c < 2; c++){
    int n = (c0 + c) * 16 + l16;
    float bv = b0[n] + b1[n];
    #pragma unroll
    for (int r4 = 0; r4 < 4; r4++){
      int row = m0 + rt * 16 + quad * 4 + r4;
      if (row < M){
        float v2 = gacc[c][r4] + bv;
        if (relu) v2 = fmaxf(v2, 0.f);
        Hout[(long long)row * F + n] = f2b(v2);
      }
    }
  }
}

// ---------------- final classifier: wave per batch row; fp32 out ----------------
__global__ void k_out(const unsigned short* __restrict__ h2,
                      const int* __restrict__ cbi,
                      const int* __restrict__ rank,
                      const float* __restrict__ Wc,
                      const float* __restrict__ bcp,
                      float* __restrict__ out){
  int w = (int)(((unsigned)blockIdx.x * blockDim.x + threadIdx.x) >> 6);
  int lane = threadIdx.x & 63;
  if (w >= BATCH) return;
  int rk = rank[cbi[w]];
  float v = b2f(h2[(long long)rk * F + lane]);
  float p0 = v * Wc[lane * 2];
  float p1 = v * Wc[lane * 2 + 1];
  for (int off = 32; off; off >>= 1){
    p0 += __shfl_xor(p0, off, 64);
    p1 += __shfl_xor(p1, off, 64);
  }
  if (lane == 0){
    out[2 * w]     = p0 + bcp[0];
    out[2 * w + 1] = p1 + bcp[1];
  }
}

extern "C" void kernel_launch(void* const* d_in, const int* in_sizes, int n_in,
                              void* d_out, int out_size, void* d_ws, size_t ws_size,
                              hipStream_t stream)
{
  const float* x_c = (const float*)d_in[0];
  const float* x_e = (const float*)d_in[1];
  const float* x_v = (const float*)d_in[2];
  const int*   ei  = (const int*)d_in[3];
  const int*   cbi = (const int*)d_in[4];
  const float* Wl1 = (const float*)d_in[5];
  const float* bl1 = (const float*)d_in[6];
  const float* Wr1 = (const float*)d_in[7];
  const float* Wl2 = (const float*)d_in[8];
  const float* bl2 = (const float*)d_in[9];
  const float* Wr2 = (const float*)d_in[10];
  const float* Wc  = (const float*)d_in[11];
  const float* bc  = (const float*)d_in[12];
  float* out = (float*)d_out;

  char* ws = (char*)d_ws;
  size_t off = 0;
  auto alloc = [&](size_t bytes) -> char* {
    char* p = ws + off;
    off += (bytes + 255) & ~(size_t)255;
    return p;
  };
  int* R       = (int*)alloc((size_t)(NT + 1) * 4);
  int* cursor  = (int*)alloc((size_t)NBKT * 4);
  int* colBase = (int*)alloc((size_t)NBKT * 4);
  unsigned int* bits = (unsigned int*)alloc((size_t)NBITS_W * 4);
  int* rank    = (int*)alloc((size_t)N_CLAIM * 4);
  int* list    = (int*)alloc((size_t)BATCH * 4);
  int* nu      = (int*)alloc(256);
  int* col     = (int*)alloc((size_t)4 * NEDGE * 4);
  unsigned int* pairs = (unsigned int*)alloc((size_t)NBKT * CAP * 4);   // dead after k_csr
  unsigned short* xb_c  = (unsigned short*)alloc((size_t)N_CLAIM    * F * 2);
  unsigned short* xb_e  = (unsigned short*)alloc((size_t)N_ENTITY   * F * 2);
  unsigned short* xb_v  = (unsigned short*)alloc((size_t)N_EVIDENCE * F * 2);
  unsigned short* h1c   = (unsigned short*)alloc((size_t)BATCH * F * 2);   // compacted
  unsigned short* h1e   = (unsigned short*)alloc((size_t)N_ENTITY   * F * 2);
  unsigned short* h1v   = (unsigned short*)alloc((size_t)N_EVIDENCE * F * 2);
  unsigned short* h2c   = (unsigned short*)pairs;   // compacted; alias dead pairs region

  hipMemsetAsync(bits, 0, (size_t)NBITS_W * 4, stream);
  hipMemsetAsync(nu, 0, 4, stream);

  k_mark<<<(BATCH + 255) / 256, 256, 0, stream>>>(cbi, bits);
  k_rank<<<(N_CLAIM + 255) / 256, 256, 0, stream>>>(bits, rank, list, nu);
  k_cast3<<<(NC4 + NE4 + NV4 + 255) / 256, 256, 0, stream>>>(x_c, x_e, x_v, xb_c, xb_e, xb_v);

  k_init<<<(NBKT + 255) / 256, 256, 0, stream>>>(cursor);
  k_bscatter<<<B3_BLOCKS, 256, 0, stream>>>(ei, bits, cursor, pairs);
  k_bscan<<<1, 1024, 0, stream>>>(cursor, colBase, R);
  k_csr<<<NBKT, 1024, 0, stream>>>(pairs, cursor, colBase, R, col);

  // ---- layer 1: claims fused agg+GEMM (compacted) ----
  k_cagg<<<(BATCH + 63) / 64, 512, 0, stream>>>(
      xb_e, xb_v, xb_c, R, col, list, nu,
      Wl1, Wl1 + 4096, Wr1, Wr1 + 4096, bl1, bl1 + 64, h1c, 1, 1);

  // ---- layer 1: entity + evidence fused agg+GEMM ----
  k_aggemm<<<NEB + NVB, 512, 0, stream>>>(
      xb_c, xb_e, xb_v, R, col, Wl1, Wr1, bl1, h1e, h1v);

  // ---- layer 2: claims fused agg+GEMM ----
  k_cagg<<<(BATCH + 63) / 64, 512, 0, stream>>>(
      h1e, h1v, h1c, R, col, list, nu,
      Wl2, Wl2 + 4096, Wr2, Wr2 + 4096, bl2, bl2 + 64, h2c, 0, 0);

  // ---- classifier ----
  k_out<<<(BATCH * 64 + 255) / 256, 256, 0, stream>>>(h2c, cbi, rank, Wc, bc, out);
}

// Round 7
// 510.274 us; speedup vs baseline: 2.2012x; 1.0071x over previous
//
#include <hip/hip_runtime.h>
#include <hip/hip_bf16.h>
#include <stdint.h>

#define N_CLAIM    100000
#define N_ENTITY   200000
#define N_EVIDENCE 150000
#define NEDGE      2000000
#define F          64
#define NT         550000      // concat dst: t0 claim [0,100K) t1 claim [100K,200K) t2 ent [200K,400K) t3 evid [400K,550K)
#define BATCH      50000

#define BSH   10
#define NBKT  538
#define CAP   24576
#define B3_BLOCKS 2000
#define B3_BPT    500          // blocks per edge type (uniform type per block)
#define B3_CHUNK  4000         // 500*4000 = 2,000,000 edges per type
#define B3_ITER   16           // 16*256 = 4096 >= 4000 (iter 15 partial)
#define NBITS_W   3136         // ceil(100000/32) words for claim bitmask
#define NEB       (N_ENTITY/64)            // 3125 entity blocks
#define NVB       ((N_EVIDENCE+63)/64)     // 2344 evidence blocks
#define NCB       ((BATCH+63)/64)          // 782 claim blocks (upper bound; M=*nu)

#define NC4 (N_CLAIM * F / 4)
#define NE4 (N_ENTITY * F / 4)
#define NV4 (N_EVIDENCE * F / 4)
#define NTOT4 (NC4 + NE4 + NV4)            // 7.2M float4 cast items
#define CASTB 6144
#define RANKB ((N_CLAIM + 255) / 256)      // 391
#define FRONTB (B3_BLOCKS + CASTB + RANKB)
#define L1B    (NCB + NEB + NVB)

// LDS tile: 64 rows x 64 shorts, 8 x 16B chunks per row, XOR swizzle (chunk ^ row&7).
#define SWZ(row, chunk) (((row) << 6) + ((((chunk) ^ ((row) & 7))) << 3))

static __device__ __forceinline__ float b2f(unsigned short u){
  return __uint_as_float(((unsigned int)u) << 16);
}
static __device__ __forceinline__ unsigned short f2b(float f){
  unsigned int x = __float_as_uint(f);
  x += 0x7fffu + ((x >> 16) & 1u);   // RNE
  return (unsigned short)(x >> 16);
}

typedef float f32x2v __attribute__((ext_vector_type(2)));

static __device__ __forceinline__ f32x2v pk_add(f32x2v a, f32x2v b){
  f32x2v d;
  asm("v_pk_add_f32 %0, %1, %2" : "=v"(d) : "v"(a), "v"(b));
  return d;
}
static __device__ __forceinline__ f32x2v unp(unsigned int w){
  f32x2v r;
  r.x = __uint_as_float(w << 16);
  r.y = __uint_as_float(w & 0xffff0000u);
  return r;
}

typedef __bf16 bf16x8 __attribute__((ext_vector_type(8)));
typedef float  f32x4  __attribute__((ext_vector_type(4)));

// ---------------- mark used claims + init bucket cursors ----------------
__global__ void k_mark(const int* __restrict__ cbi, unsigned int* __restrict__ bits,
                       int* __restrict__ cursor){
  int i = blockIdx.x * blockDim.x + threadIdx.x;
  if (i < NBKT) cursor[i] = i * CAP;
  if (i < BATCH){
    int c = cbi[i];
    atomicOr(&bits[c >> 5], 1u << (c & 31));
  }
}

// ---------------- front mega-kernel: bscatter | cast3 | rank (independent) ----------------
__global__ __launch_bounds__(256) void k_front(const int* __restrict__ ei,
                                               const unsigned int* __restrict__ bits,
                                               int* __restrict__ cursor,
                                               unsigned int* __restrict__ pairs,
                                               const float* __restrict__ xc,
                                               const float* __restrict__ xe,
                                               const float* __restrict__ xv,
                                               unsigned short* __restrict__ oc,
                                               unsigned short* __restrict__ oe,
                                               unsigned short* __restrict__ ov,
                                               int* __restrict__ rank,
                                               int* __restrict__ list,
                                               int* __restrict__ nu){
  __shared__ int hl[2 * NBKT];
  int tid = threadIdx.x;
  int bid = blockIdx.x;
  if (bid < B3_BLOCKS){
    // ---- phase-separated register-resident bucket scatter ----
    int* hcnt = hl;
    int* hpos = hl + NBKT;
    const int toff[4] = {0, N_CLAIM, 2*N_CLAIM, 2*N_CLAIM + N_ENTITY};
    int bpt = bid / B3_BPT;
    int e0  = (bid - bpt * B3_BPT) * B3_CHUNK;
    int off_t = toff[bpt];
    bool isclaim = (bpt < 2);
    const int* dstp = ei + (size_t)bpt * 2 * NEDGE + NEDGE + e0;
    const int* srcp = ei + (size_t)bpt * 2 * NEDGE + e0;
    for (int b = tid; b < NBKT; b += 256) hcnt[b] = 0;
    __syncthreads();
    unsigned int v[B3_ITER];
    #pragma unroll
    for (int i = 0; i < B3_ITER; ++i){
      int li = i * 256 + tid;
      v[i] = 0xFFFFFFFFu;
      if (li < B3_CHUNK){
        int dst = dstp[li];
        if (!isclaim || ((bits[dst >> 5] >> (dst & 31)) & 1u))
          v[i] = (unsigned int)(dst + off_t);
      }
    }
    #pragma unroll
    for (int i = 0; i < B3_ITER; ++i)
      if (v[i] != 0xFFFFFFFFu) atomicAdd(&hcnt[v[i] >> BSH], 1);
    __syncthreads();
    for (int b = tid; b < NBKT; b += 256){
      int c = hcnt[b];
      hpos[b] = c ? atomicAdd(&cursor[b], c) : 0;
    }
    __syncthreads();
    int s[B3_ITER];
    #pragma unroll
    for (int i = 0; i < B3_ITER; ++i){
      int li = i * 256 + tid;
      s[i] = (li < B3_CHUNK) ? srcp[li] : 0;
    }
    #pragma unroll
    for (int i = 0; i < B3_ITER; ++i){
      if (v[i] != 0xFFFFFFFFu){
        int o = atomicAdd(&hpos[v[i] >> BSH], 1);
        pairs[o] = ((v[i] & ((1u << BSH) - 1)) << 18) | (unsigned int)s[i];
      }
    }
  } else if (bid < B3_BLOCKS + CASTB){
    // ---- fp32 -> bf16 cast, grid-strided over all three tables ----
    int cb = bid - B3_BLOCKS;
    for (int i = cb * 256 + tid; i < NTOT4; i += CASTB * 256){
      const float* in; unsigned short* out; int j;
      if (i < NC4){ in = xc; out = oc; j = i; }
      else if (i < NC4 + NE4){ in = xe; out = oe; j = i - NC4; }
      else { in = xv; out = ov; j = i - NC4 - NE4; }
      float4 v = ((const float4*)in)[j];
      ushort4 o;
      o.x = f2b(v.x); o.y = f2b(v.y); o.z = f2b(v.z); o.w = f2b(v.w);
      ((ushort4*)out)[j] = o;
    }
  } else {
    // ---- rank/compact used claims ----
    int i = (bid - B3_BLOCKS - CASTB) * 256 + tid;
    if (i < N_CLAIM && ((bits[i >> 5] >> (i & 31)) & 1u)){
      int r = atomicAdd(nu, 1);
      rank[i] = r;
      list[r] = i;
    }
  }
}

// ---------------- CSR finalize: per-block self-scan of bucket counts ----------------
__global__ __launch_bounds__(1024) void k_csr(const unsigned int* __restrict__ pairs,
                                              const int* __restrict__ cursor,
                                              int* __restrict__ R, int* __restrict__ col){
  __shared__ int h[1024];
  __shared__ int s[1024];
  int b = blockIdx.x, tid = threadIdx.x;
  // scan all bucket counts locally -> base for this bucket (+ R[NT] once)
  int cb = (tid < NBKT) ? (cursor[tid] - tid * CAP) : 0;
  s[tid] = cb;
  __syncthreads();
  for (int off = 1; off < 1024; off <<= 1){
    int t = (tid >= off) ? s[tid - off] : 0;
    __syncthreads();
    s[tid] += t;
    __syncthreads();
  }
  int cnt  = cursor[b] - b * CAP;
  int base = s[b] - cnt;                 // exclusive prefix at bucket b (uniform read)
  if (b == 0 && tid == 1023) R[NT] = s[1023];
  __syncthreads();
  int pbase = b * CAP;
  h[tid] = 0;
  __syncthreads();
  for (int i = tid; i < cnt; i += 1024)
    atomicAdd(&h[pairs[pbase + i] >> 18], 1);
  __syncthreads();
  int c = h[tid];
  s[tid] = c;
  __syncthreads();
  for (int off = 1; off < 1024; off <<= 1){
    int t = (tid >= off) ? s[tid - off] : 0;
    __syncthreads();
    s[tid] += t;
    __syncthreads();
  }
  int ex = s[tid] - c;
  h[tid] = ex;
  int n = (b << BSH) + tid;
  if (n < NT) R[n] = base + ex;
  __syncthreads();
  for (int i = tid; i < cnt; i += 1024){
    unsigned int p = pairs[pbase + i];
    int r = atomicAdd(&h[p >> 18], 1);
    col[base + r] = (int)(p & 0x3FFFFu);
  }
}

// ---- shared helpers for the fused agg+GEMM kernels ----
static __device__ __forceinline__ void stage_w(const float* __restrict__ W,
                                               unsigned short* __restrict__ T,
                                               int n, int oct){
  unsigned int pk[4];
  #pragma unroll
  for (int i = 0; i < 4; i++){
    float lo = W[(oct * 8 + 2 * i)     * 64 + n];
    float hi = W[(oct * 8 + 2 * i + 1) * 64 + n];
    pk[i] = ((unsigned int)f2b(hi) << 16) | f2b(lo);
  }
  *(uint4*)(T + SWZ(n, oct)) = *(uint4*)pk;
}

static __device__ __forceinline__ void gather_mean(
    const unsigned short* __restrict__ X, const int* __restrict__ col,
    int rbeg, int rend, int g, int fl, f32x2v acc[4]){
  int cid = 0;
  int deg = rend - rbeg;
  if (fl < deg) cid = col[rbeg + fl];
  for (int p = rbeg; p < rend; p += 8){
    int nb = rend - p; if (nb > 8) nb = 8;
    int cc = cid;
    int rem = rend - (p + 8);
    if (rem > 0 && fl < rem) cid = col[p + 8 + fl];
    #pragma unroll
    for (int k = 0; k < 8; ++k){
      int c = __shfl(cc, (g << 3) + k, 64);
      if (k < nb){
        uint4 d = *(const uint4*)(X + (long long)c * F + fl * 8);
        acc[0] = pk_add(acc[0], unp(d.x));
        acc[1] = pk_add(acc[1], unp(d.y));
        acc[2] = pk_add(acc[2], unp(d.z));
        acc[3] = pk_add(acc[3], unp(d.w));
      }
    }
  }
}

static __device__ __forceinline__ uint4 mean_pack(f32x2v acc[4], int deg){
  float r = deg ? (1.0f / (float)deg) : 0.f;
  uint4 o;
  o.x = ((unsigned int)f2b(acc[0].y * r) << 16) | f2b(acc[0].x * r);
  o.y = ((unsigned int)f2b(acc[1].y * r) << 16) | f2b(acc[1].x * r);
  o.z = ((unsigned int)f2b(acc[2].y * r) << 16) | f2b(acc[2].x * r);
  o.w = ((unsigned int)f2b(acc[3].y * r) << 16) | f2b(acc[3].x * r);
  return o;
}

// ---- entity/evidence fused agg+GEMM body (LDS: 3*4096 shorts used) ----
static __device__ __forceinline__ void aggemm_body(int b, unsigned short* L,
    const unsigned short* __restrict__ Xg,
    const unsigned short* __restrict__ Xe, const unsigned short* __restrict__ Xv,
    const int* __restrict__ R, const int* __restrict__ col,
    const float* __restrict__ Wl, const float* __restrict__ Wr,
    const float* __restrict__ bl,
    unsigned short* __restrict__ He, unsigned short* __restrict__ Hv)
{
  unsigned short* WTm = L;
  unsigned short* WTr = L + 4096;
  unsigned short* MT  = L + 2 * 4096;
  int seg, m0, Rb, Ms;
  const unsigned short* Xroot;
  unsigned short* Hout;
  if (b < NEB){ seg = 0; m0 = b * 64;         Rb = 2*N_CLAIM;            Ms = N_ENTITY;   Xroot = Xe; Hout = He; }
  else        { seg = 1; m0 = (b - NEB) * 64; Rb = 2*N_CLAIM + N_ENTITY; Ms = N_EVIDENCE; Xroot = Xv; Hout = Hv; }
  int tid = threadIdx.x;
  int sn = tid & 63, soct = tid >> 6;
  stage_w(Wl + (size_t)(2 + seg) * 4096, WTm, sn, soct);
  stage_w(Wr + (size_t)(2 + seg) * 4096, WTr, sn, soct);
  int lane = tid & 63;
  int wv   = tid >> 6;
  int g    = lane >> 3;
  int fl   = lane & 7;
  int rowl = wv * 8 + g;
  int rowg = m0 + rowl;
  bool act = rowg < Ms;
  int rbeg = 0, rend = 0;
  if (act){ rbeg = R[Rb + rowg]; rend = R[Rb + rowg + 1]; }
  f32x2v z = {0.f, 0.f};
  f32x2v acc[4] = {z, z, z, z};
  gather_mean(Xg, col, rbeg, rend, g, fl, acc);
  *(uint4*)(MT + SWZ(rowl, fl)) = mean_pack(acc, rend - rbeg);
  __syncthreads();
  int rt = wv >> 1;
  int c0 = (wv & 1) * 2;
  int quad = lane >> 4, l16 = lane & 15;
  int arow = m0 + rt * 16 + l16; if (arow >= Ms) arow = Ms - 1;
  f32x4 zz = {0.f, 0.f, 0.f, 0.f};
  f32x4 gacc[2] = {zz, zz};
  #pragma unroll
  for (int kk = 0; kk < 64; kk += 32){
    int ch = (kk >> 3) + quad;
    bf16x8 am = *(const bf16x8*)(MT + SWZ(rt * 16 + l16, ch));
    bf16x8 ar = *(const bf16x8*)(Xroot + (long long)arow * F + kk + quad * 8);
    #pragma unroll
    for (int c = 0; c < 2; c++){
      int bn = (c0 + c) * 16 + l16;
      bf16x8 bm = *(const bf16x8*)(WTm + SWZ(bn, ch));
      bf16x8 br = *(const bf16x8*)(WTr + SWZ(bn, ch));
      gacc[c] = __builtin_amdgcn_mfma_f32_16x16x32_bf16(am, bm, gacc[c], 0, 0, 0);
      gacc[c] = __builtin_amdgcn_mfma_f32_16x16x32_bf16(ar, br, gacc[c], 0, 0, 0);
    }
  }
  const float* blp = bl + (size_t)(2 + seg) * 64;
  #pragma unroll
  for (int c = 0; c < 2; c++){
    int n = (c0 + c) * 16 + l16;
    float bv = blp[n];
    #pragma unroll
    for (int r4 = 0; r4 < 4; r4++){
      int row = m0 + rt * 16 + quad * 4 + r4;
      if (row < Ms){
        float v2 = gacc[c][r4] + bv;
        Hout[(long long)row * F + n] = f2b(fmaxf(v2, 0.f));
      }
    }
  }
}

// ---- claims fused agg+GEMM body (LDS: 6*4096 shorts used) ----
static __device__ __forceinline__ void cagg_body(int bid, unsigned short* L,
    const unsigned short* __restrict__ Xg0, const unsigned short* __restrict__ Xg1,
    const unsigned short* __restrict__ Xr,
    const int* __restrict__ R, const int* __restrict__ col,
    const int* __restrict__ list, const int* __restrict__ nu_ptr,
    const float* __restrict__ W0, const float* __restrict__ W1,
    const float* __restrict__ W2, const float* __restrict__ W3,
    const float* __restrict__ b0, const float* __restrict__ b1,
    unsigned short* __restrict__ Hout, int rootlist, int relu)
{
  int M = *nu_ptr;
  if (bid * 64 >= M) return;
  unsigned short* WT = L;
  unsigned short* MT = L + 4 * 4096;
  int tid = threadIdx.x;
  int sn = tid & 63, soct = tid >> 6;
  stage_w(W0, WT,            sn, soct);
  stage_w(W1, WT + 4096,     sn, soct);
  stage_w(W2, WT + 2 * 4096, sn, soct);
  stage_w(W3, WT + 3 * 4096, sn, soct);
  int m0 = bid * 64;
  int lane = tid & 63;
  int wv   = tid >> 6;
  int g    = lane >> 3;
  int fl   = lane & 7;
  int rowl = wv * 8 + g;
  int rowg = m0 + rowl;
  bool act = rowg < M;
  int node0 = act ? list[rowg] : 0;
  #pragma unroll
  for (int seg = 0; seg < 2; ++seg){
    const unsigned short* Xg = seg ? Xg1 : Xg0;
    int node = node0 + (seg ? N_CLAIM : 0);
    int rbeg = 0, rend = 0;
    if (act){ rbeg = R[node]; rend = R[node + 1]; }
    f32x2v z = {0.f, 0.f};
    f32x2v acc[4] = {z, z, z, z};
    gather_mean(Xg, col, rbeg, rend, g, fl, acc);
    *(uint4*)(MT + seg * 4096 + SWZ(rowl, fl)) = mean_pack(acc, rend - rbeg);
  }
  __syncthreads();
  int rt = wv >> 1;
  int c0 = (wv & 1) * 2;
  int quad = lane >> 4, l16 = lane & 15;
  int arow = m0 + rt * 16 + l16; if (arow >= M) arow = M - 1;
  long long rrow = rootlist ? list[arow] : arow;
  f32x4 zz = {0.f, 0.f, 0.f, 0.f};
  f32x4 gacc[2] = {zz, zz};
  #pragma unroll
  for (int kk = 0; kk < 64; kk += 32){
    int ch = (kk >> 3) + quad;
    bf16x8 a0 = *(const bf16x8*)(MT + SWZ(rt * 16 + l16, ch));
    bf16x8 a1 = *(const bf16x8*)(MT + 4096 + SWZ(rt * 16 + l16, ch));
    bf16x8 ar = *(const bf16x8*)(Xr + rrow * F + kk + quad * 8);
    #pragma unroll
    for (int c = 0; c < 2; c++){
      int bn = (c0 + c) * 16 + l16;
      bf16x8 w0 = *(const bf16x8*)(WT +            SWZ(bn, ch));
      bf16x8 w1 = *(const bf16x8*)(WT + 4096     + SWZ(bn, ch));
      bf16x8 w2 = *(const bf16x8*)(WT + 2 * 4096 + SWZ(bn, ch));
      bf16x8 w3 = *(const bf16x8*)(WT + 3 * 4096 + SWZ(bn, ch));
      gacc[c] = __builtin_amdgcn_mfma_f32_16x16x32_bf16(a0, w0, gacc[c], 0, 0, 0);
      gacc[c] = __builtin_amdgcn_mfma_f32_16x16x32_bf16(a1, w1, gacc[c], 0, 0, 0);
      gacc[c] = __builtin_amdgcn_mfma_f32_16x16x32_bf16(ar, w2, gacc[c], 0, 0, 0);
      gacc[c] = __builtin_amdgcn_mfma_f32_16x16x32_bf16(ar, w3, gacc[c], 0, 0, 0);
    }
  }
  #pragma unroll
  for (int c = 0; c < 2; c++){
    int n = (c0 + c) * 16 + l16;
    float bv = b0[n] + b1[n];
    #pragma unroll
    for (int r4 = 0; r4 < 4; r4++){
      int row = m0 + rt * 16 + quad * 4 + r4;
      if (row < M){
        float v2 = gacc[c][r4] + bv;
        if (relu) v2 = fmaxf(v2, 0.f);
        Hout[(long long)row * F + n] = f2b(v2);
      }
    }
  }
}

// ---------------- layer-1 mega-kernel: claims cagg | ent/evid aggemm ----------------
__global__ __launch_bounds__(512) void k_l1(
    const int* __restrict__ R, const int* __restrict__ col,
    const unsigned short* __restrict__ xb_c, const unsigned short* __restrict__ xb_e,
    const unsigned short* __restrict__ xb_v,
    const int* __restrict__ list, const int* __restrict__ nu,
    const float* __restrict__ Wl1, const float* __restrict__ Wr1,
    const float* __restrict__ bl1,
    unsigned short* __restrict__ h1c, unsigned short* __restrict__ h1e,
    unsigned short* __restrict__ h1v)
{
  __shared__ __align__(16) unsigned short L[6 * 4096];
  int bid = blockIdx.x;
  if (bid < NCB){
    cagg_body(bid, L, xb_e, xb_v, xb_c, R, col, list, nu,
              Wl1, Wl1 + 4096, Wr1, Wr1 + 4096, bl1, bl1 + 64, h1c, 1, 1);
  } else {
    aggemm_body(bid - NCB, L, xb_c, xb_e, xb_v, R, col, Wl1, Wr1, bl1, h1e, h1v);
  }
}

// ---------------- layer-2 claims kernel ----------------
__global__ __launch_bounds__(512) void k_cagg2(
    const unsigned short* __restrict__ h1e, const unsigned short* __restrict__ h1v,
    const unsigned short* __restrict__ h1c,
    const int* __restrict__ R, const int* __restrict__ col,
    const int* __restrict__ list, const int* __restrict__ nu,
    const float* __restrict__ Wl2, const float* __restrict__ Wr2,
    const float* __restrict__ bl2,
    unsigned short* __restrict__ h2c)
{
  __shared__ __align__(16) unsigned short L[6 * 4096];
  cagg_body(blockIdx.x, L, h1e, h1v, h1c, R, col, list, nu,
            Wl2, Wl2 + 4096, Wr2, Wr2 + 4096, bl2, bl2 + 64, h2c, 0, 0);
}

// ---------------- final classifier: wave per batch row; fp32 out ----------------
__global__ void k_out(const unsigned short* __restrict__ h2,
                      const int* __restrict__ cbi,
                      const int* __restrict__ rank,
                      const float* __restrict__ Wc,
                      const float* __restrict__ bcp,
                      float* __restrict__ out){
  int w = (int)(((unsigned)blockIdx.x * blockDim.x + threadIdx.x) >> 6);
  int lane = threadIdx.x & 63;
  if (w >= BATCH) return;
  int rk = rank[cbi[w]];
  float v = b2f(h2[(long long)rk * F + lane]);
  float p0 = v * Wc[lane * 2];
  float p1 = v * Wc[lane * 2 + 1];
  for (int off = 32; off; off >>= 1){
    p0 += __shfl_xor(p0, off, 64);
    p1 += __shfl_xor(p1, off, 64);
  }
  if (lane == 0){
    out[2 * w]     = p0 + bcp[0];
    out[2 * w + 1] = p1 + bcp[1];
  }
}

extern "C" void kernel_launch(void* const* d_in, const int* in_sizes, int n_in,
                              void* d_out, int out_size, void* d_ws, size_t ws_size,
                              hipStream_t stream)
{
  const float* x_c = (const float*)d_in[0];
  const float* x_e = (const float*)d_in[1];
  const float* x_v = (const float*)d_in[2];
  const int*   ei  = (const int*)d_in[3];
  const int*   cbi = (const int*)d_in[4];
  const float* Wl1 = (const float*)d_in[5];
  const float* bl1 = (const float*)d_in[6];
  const float* Wr1 = (const float*)d_in[7];
  const float* Wl2 = (const float*)d_in[8];
  const float* bl2 = (const float*)d_in[9];
  const float* Wr2 = (const float*)d_in[10];
  const float* Wc  = (const float*)d_in[11];
  const float* bc  = (const float*)d_in[12];
  float* out = (float*)d_out;

  char* ws = (char*)d_ws;
  size_t off = 0;
  auto alloc = [&](size_t bytes) -> char* {
    char* p = ws + off;
    off += (bytes + 255) & ~(size_t)255;
    return p;
  };
  int* R       = (int*)alloc((size_t)(NT + 1) * 4);
  int* cursor  = (int*)alloc((size_t)NBKT * 4);
  unsigned int* bits = (unsigned int*)alloc((size_t)NBITS_W * 4);
  int* rank    = (int*)alloc((size_t)N_CLAIM * 4);
  int* list    = (int*)alloc((size_t)BATCH * 4);
  int* nu      = (int*)alloc(256);
  int* col     = (int*)alloc((size_t)4 * NEDGE * 4);
  unsigned int* pairs = (unsigned int*)alloc((size_t)NBKT * CAP * 4);   // dead after k_csr
  unsigned short* xb_c  = (unsigned short*)alloc((size_t)N_CLAIM    * F * 2);
  unsigned short* xb_e  = (unsigned short*)alloc((size_t)N_ENTITY   * F * 2);
  unsigned short* xb_v  = (unsigned short*)alloc((size_t)N_EVIDENCE * F * 2);
  unsigned short* h1c   = (unsigned short*)alloc((size_t)BATCH * F * 2);   // compacted
  unsigned short* h1e   = (unsigned short*)alloc((size_t)N_ENTITY   * F * 2);
  unsigned short* h1v   = (unsigned short*)alloc((size_t)N_EVIDENCE * F * 2);
  unsigned short* h2c   = (unsigned short*)pairs;   // compacted; alias dead pairs region

  hipMemsetAsync(bits, 0, (size_t)NBITS_W * 4, stream);
  hipMemsetAsync(nu, 0, 4, stream);

  k_mark<<<(BATCH + 255) / 256, 256, 0, stream>>>(cbi, bits, cursor);

  k_front<<<FRONTB, 256, 0, stream>>>(ei, bits, cursor, pairs,
      x_c, x_e, x_v, xb_c, xb_e, xb_v, rank, list, nu);

  k_csr<<<NBKT, 1024, 0, stream>>>(pairs, cursor, R, col);

  k_l1<<<L1B, 512, 0, stream>>>(R, col, xb_c, xb_e, xb_v, list, nu,
      Wl1, Wr1, bl1, h1c, h1e, h1v);

  k_cagg2<<<NCB, 512, 0, stream>>>(h1e, h1v, h1c, R, col, list, nu,
      Wl2, Wr2, bl2, h2c);

  k_out<<<(BATCH * 64 + 255) / 256, 256, 0, stream>>>(h2c, cbi, rank, Wc, bc, out);
}